// Round 1
// baseline (626.732 us; speedup 1.0000x reference)
//
#include <hip/hip_runtime.h>

// ---------------------------------------------------------------------------
// GNNPerAgentModel: CNN(3 conv + proj) -> per-batch GAT row (agent only) -> MLP head
// Round 0: fp32 baseline. Batch-minor layout for conv chain: activations stored
// [channel*spatial][batch]; lanes = batch  => coalesced vector loads, wave-uniform
// weights => scalar s_loads, no LDS. All accumulators in registers.
// ---------------------------------------------------------------------------

__global__ __launch_bounds__(256) void prep_weights(
    const float* __restrict__ W1, const float* __restrict__ W2, const float* __restrict__ W3,
    float* __restrict__ W1t, float* __restrict__ W2t, float* __restrict__ W3t)
{
    int i = blockIdx.x * 256 + threadIdx.x;
    if (i < 6144) {                       // W1t[((kh*8+kw)*3+c)*32+oc] = W1[oc][c][kh][kw]
        int oc = i & 31, q = i >> 5;
        int c = q % 3, kk = q / 3;
        int kw = kk & 7, kh = kk >> 3;
        W1t[i] = W1[((oc * 3 + c) * 8 + kh) * 8 + kw];
    } else if (i < 6144 + 32768) {        // W2t[((ic*4+kh)*4+kw)*64+oc] = W2[oc][ic][kh][kw]
        int j = i - 6144;
        int oc = j & 63, q = j >> 6;
        int kw = q & 3, kh = (q >> 2) & 3, ic = q >> 4;
        W2t[j] = W2[((oc * 32 + ic) * 4 + kh) * 4 + kw];
    } else if (i < 6144 + 32768 + 36864) { // W3t[((ic*3+kh)*3+kw)*64+oc] = W3[oc][ic][kh][kw]
        int j = i - 6144 - 32768;
        int oc = j & 63, q = j >> 6;
        int kw = q % 3, t2 = q / 3, kh = t2 % 3, ic = t2 / 3;
        W3t[j] = W3[((oc * 64 + ic) * 3 + kh) * 3 + kw];
    }
}

// cam [512][84*84*3] -> camt [21168][BC]  (chunk-local batch minor)
__global__ __launch_bounds__(256) void transpose_cam(
    const float* __restrict__ cam, float* __restrict__ camt, int b0, int BC)
{
    __shared__ float tile[32][33];
    int pt = blockIdx.x * 32;
    int bb = blockIdx.y * 32;            // chunk-local batch base
    int tx = threadIdx.x, ty = threadIdx.y;
    #pragma unroll
    for (int i = 0; i < 4; i++) {
        int bl = ty + i * 8;
        int p = pt + tx;
        float v = (p < 21168) ? cam[(b0 + bb + bl) * 21168 + p] : 0.f;
        tile[bl][tx] = v;
    }
    __syncthreads();
    #pragma unroll
    for (int i = 0; i < 4; i++) {
        int pl = ty + i * 8;
        int p = pt + pl;
        if (p < 21168) camt[p * BC + bb + tx] = tile[tx][pl];
    }
}

// conv1: 3ch 84x84 -> 32ch 39x39, k=8 s=2, relu.  thread = (spatial s, batch lane)
__global__ __launch_bounds__(256) void conv1_k(
    const float* __restrict__ camt, const float* __restrict__ W1t,
    const float* __restrict__ b1, float* __restrict__ out1, int BC)
{
    int s = blockIdx.x;                              // 0..1520
    int bl = blockIdx.y * blockDim.x + threadIdx.x;  // 0..BC-1
    int oh = s / 39, ow = s % 39;
    float acc[32];
    #pragma unroll
    for (int oc = 0; oc < 32; oc++) acc[oc] = b1[oc];
    const int p0 = (2 * oh * 84 + 2 * ow) * 3;
    for (int kh = 0; kh < 8; kh++) {
        const float* ip = camt + (p0 + kh * 252) * BC + bl;
        const float* wp = W1t + kh * 768;
        #pragma unroll 4
        for (int r = 0; r < 24; r++) {               // r = kw*3 + c
            float inv = ip[r * BC];
            #pragma unroll
            for (int oc = 0; oc < 32; oc++) acc[oc] += inv * wp[r * 32 + oc];
        }
    }
    #pragma unroll
    for (int oc = 0; oc < 32; oc++)
        out1[(oc * 1521 + s) * BC + bl] = fmaxf(acc[oc], 0.f);
}

// conv2: 32ch 39x39 -> 64ch 18x18, k=4 s=2, relu
__global__ __launch_bounds__(256) void conv2_k(
    const float* __restrict__ in, const float* __restrict__ W2t,
    const float* __restrict__ b2, float* __restrict__ out2, int BC)
{
    int s = blockIdx.x;                              // 0..323
    int bl = blockIdx.y * blockDim.x + threadIdx.x;
    int oh = s / 18, ow = s % 18;
    float acc[64];
    #pragma unroll
    for (int oc = 0; oc < 64; oc++) acc[oc] = b2[oc];
    for (int ic = 0; ic < 32; ic++) {
        #pragma unroll
        for (int kh = 0; kh < 4; kh++) {
            const float* ip = in + (ic * 1521 + (2 * oh + kh) * 39 + 2 * ow) * BC + bl;
            const float* wp = W2t + (ic * 16 + kh * 4) * 64;
            #pragma unroll
            for (int kw = 0; kw < 4; kw++) {
                float inv = ip[kw * BC];
                #pragma unroll
                for (int oc = 0; oc < 64; oc++) acc[oc] += inv * wp[kw * 64 + oc];
            }
        }
    }
    #pragma unroll
    for (int oc = 0; oc < 64; oc++)
        out2[(oc * 324 + s) * BC + bl] = fmaxf(acc[oc], 0.f);
}

// conv3: 64ch 18x18 -> 64ch 16x16, k=3 s=1, relu; writes x3 as [k=c*256+s][b]
__global__ __launch_bounds__(256) void conv3_k(
    const float* __restrict__ in, const float* __restrict__ W3t,
    const float* __restrict__ b3, float* __restrict__ x3, int BC)
{
    int s = blockIdx.x;                              // 0..255
    int bl = blockIdx.y * blockDim.x + threadIdx.x;
    int oh = s >> 4, ow = s & 15;
    float acc[64];
    #pragma unroll
    for (int oc = 0; oc < 64; oc++) acc[oc] = b3[oc];
    for (int ic = 0; ic < 64; ic++) {
        #pragma unroll
        for (int kh = 0; kh < 3; kh++) {
            const float* ip = in + (ic * 324 + (oh + kh) * 18 + ow) * BC + bl;
            const float* wp = W3t + (ic * 9 + kh * 3) * 64;
            #pragma unroll
            for (int kw = 0; kw < 3; kw++) {
                float inv = ip[kw * BC];
                #pragma unroll
                for (int oc = 0; oc < 64; oc++) acc[oc] += inv * wp[kw * 64 + oc];
            }
        }
    }
    #pragma unroll
    for (int oc = 0; oc < 64; oc++)
        x3[(oc * 256 + s) * BC + bl] = fmaxf(acc[oc], 0.f);
}

// proj partial: x3[k][b] (K=16384) x Wp[k][256] -> partial[kseg-row n][b], K split 64
__global__ __launch_bounds__(256) void proj_k(
    const float* __restrict__ x3, const float* __restrict__ Wp,
    float* __restrict__ partial, int BC)
{
    int nq = blockIdx.x & 3, ks = blockIdx.x >> 2;   // nq: n-quarter, ks: 0..63
    int bl = blockIdx.y * blockDim.x + threadIdx.x;
    float acc[64];
    #pragma unroll
    for (int j = 0; j < 64; j++) acc[j] = 0.f;
    int k0 = ks * 256;
    for (int kk = 0; kk < 256; kk++) {
        int k = k0 + kk;
        float inv = x3[k * BC + bl];
        const float* wp = Wp + k * 256 + nq * 64;
        #pragma unroll
        for (int j = 0; j < 64; j++) acc[j] += inv * wp[j];
    }
    #pragma unroll
    for (int j = 0; j < 64; j++)
        partial[(ks * 256 + nq * 64 + j) * BC + bl] = acc[j];
}

__global__ __launch_bounds__(256) void reduce_k(
    const float* __restrict__ partial, const float* __restrict__ bp,
    float* __restrict__ camfeat, int b0, int BC)
{
    int i = blockIdx.x * 256 + threadIdx.x;
    int bl = i % BC;                                 // BC is pow2
    int n = i / BC;
    float s = 0.f;
    for (int ks = 0; ks < 64; ks++) s += partial[(ks * 256 + n) * BC + bl];
    camfeat[(b0 + bl) * 256 + n] = fmaxf(s + bp[n], 0.f);
}

// GAT (agent row only) + id-embed + MLP head. One block per batch element.
__global__ __launch_bounds__(256) void gat_head(
    const float* __restrict__ camfeat, const float* __restrict__ pos,
    const float* __restrict__ tpos, const int* __restrict__ aidx,
    const float* __restrict__ Wg, const float* __restrict__ asrc, const float* __restrict__ adst,
    const float* __restrict__ Wid, const float* __restrict__ bid,
    const float* __restrict__ Wh1, const float* __restrict__ bh1,
    const float* __restrict__ Wh2, const float* __restrict__ bh2,
    float* __restrict__ out)
{
    int b = blockIdx.x, t = threadIdx.x;
    __shared__ float cf[256];
    __shared__ float hN[16][256];
    __shared__ float srcv[16][2], dstv[16][2];
    __shared__ float alpha[16][2];
    __shared__ float af[320];
    __shared__ float zz[256];
    __shared__ unsigned int adjm_s;

    int ai = aidx[b];
    cf[t] = camfeat[b * 256 + t];
    __syncthreads();

    // hN base: cam_feat @ Wg[:256]  (thread t = output column)
    float basev = 0.f;
    for (int k = 0; k < 256; k++) basev += cf[k] * Wg[k * 256 + t];

    float rw0 = Wg[256 * 256 + t], rw1 = Wg[257 * 256 + t], rw2 = Wg[258 * 256 + t];
    float px = pos[b * 3 + 0], py = pos[b * 3 + 1], pz = pos[b * 3 + 2];
    for (int n = 0; n < 16; n++) {
        float r0 = tpos[(b * 16 + n) * 3 + 0] - px;
        float r1 = tpos[(b * 16 + n) * 3 + 1] - py;
        float r2 = tpos[(b * 16 + n) * 3 + 2] - pz;
        hN[n][t] = basev + r0 * rw0 + r1 * rw1 + r2 * rw2;
    }

    // adjacency mask for agent row (wave 0): dist<100, no self; self-loop if isolated
    if (t < 64) {
        bool on = false;
        if (t < 16 && t != ai) {
            float dx = tpos[(b * 16 + ai) * 3 + 0] - tpos[(b * 16 + t) * 3 + 0];
            float dy = tpos[(b * 16 + ai) * 3 + 1] - tpos[(b * 16 + t) * 3 + 1];
            float dz = tpos[(b * 16 + ai) * 3 + 2] - tpos[(b * 16 + t) * 3 + 2];
            on = (dx * dx + dy * dy + dz * dz) < 10000.0f;
        }
        unsigned long long m = __ballot(on);
        if (t == 0) adjm_s = (m == 0ull) ? (1u << ai) : (unsigned int)m;
    }
    __syncthreads();

    // src/dst attention scalars per (j, head): 8 lanes per pair
    {
        int p = t >> 3, sub = t & 7;
        int j = p >> 1, h = p & 1;
        float s1 = 0.f, s2 = 0.f;
        #pragma unroll
        for (int dd = 0; dd < 16; dd++) {
            int d = h * 128 + sub * 16 + dd;
            float v = hN[j][d];
            s1 += v * asrc[d];
            s2 += v * adst[d];
        }
        s1 += __shfl_xor(s1, 1); s1 += __shfl_xor(s1, 2); s1 += __shfl_xor(s1, 4);
        s2 += __shfl_xor(s2, 1); s2 += __shfl_xor(s2, 2); s2 += __shfl_xor(s2, 4);
        if (sub == 0) { srcv[j][h] = s1; dstv[j][h] = s2; }
    }
    __syncthreads();

    // masked softmax over j (16 lanes per head, wave 0)
    if (t < 32) {
        int j = t & 15, h = t >> 4;
        unsigned int am = adjm_s;
        float e = srcv[ai][h] + dstv[j][h];
        e = (e > 0.f) ? e : 0.2f * e;                // leaky_relu 0.2
        e = ((am >> j) & 1u) ? e : -1e9f;
        float mx = e;
        mx = fmaxf(mx, __shfl_xor(mx, 1));
        mx = fmaxf(mx, __shfl_xor(mx, 2));
        mx = fmaxf(mx, __shfl_xor(mx, 4));
        mx = fmaxf(mx, __shfl_xor(mx, 8));
        float ex = __expf(e - mx);
        float sm = ex;
        sm += __shfl_xor(sm, 1); sm += __shfl_xor(sm, 2);
        sm += __shfl_xor(sm, 4); sm += __shfl_xor(sm, 8);
        alpha[j][h] = ex / sm;
    }
    __syncthreads();

    // aggregate agent row, elu
    {
        int h = t >> 7;
        float o = 0.f;
        #pragma unroll
        for (int j = 0; j < 16; j++) o += alpha[j][h] * hN[j][t];
        o = (o > 0.f) ? o : (__expf(o) - 1.f);       // elu (finite -> nan_to_num no-op)
        af[t] = o;
    }
    if (t < 64) {
        float v = (float)ai * Wid[t] + bid[t];
        af[256 + t] = fmaxf(v, 0.f);
    }
    __syncthreads();

    float zv = bh1[t];
    for (int k = 0; k < 320; k++) zv += af[k] * Wh1[k * 256 + t];
    zz[t] = fmaxf(zv, 0.f);
    __syncthreads();

    if (t < 6) {
        float lv = bh2[t];
        for (int k = 0; k < 256; k++) lv += zz[k] * Wh2[k * 6 + t];
        out[b * 6 + t] = lv;
    }
}

extern "C" void kernel_launch(void* const* d_in, const int* in_sizes, int n_in,
                              void* d_out, int out_size, void* d_ws, size_t ws_size,
                              hipStream_t stream)
{
    const float* cam  = (const float*)d_in[0];
    const float* pos  = (const float*)d_in[1];
    const float* tpos = (const float*)d_in[2];
    const int*   aidx = (const int*)d_in[3];
    const float* W1   = (const float*)d_in[4];
    const float* b1   = (const float*)d_in[5];
    const float* W2   = (const float*)d_in[6];
    const float* b2   = (const float*)d_in[7];
    const float* W3   = (const float*)d_in[8];
    const float* b3   = (const float*)d_in[9];
    const float* Wp   = (const float*)d_in[10];
    const float* bp   = (const float*)d_in[11];
    const float* Wid  = (const float*)d_in[12];
    const float* bid  = (const float*)d_in[13];
    const float* Wg   = (const float*)d_in[14];
    const float* asrc = (const float*)d_in[15];
    const float* adst = (const float*)d_in[16];
    const float* Wh1  = (const float*)d_in[17];
    const float* bh1  = (const float*)d_in[18];
    const float* Wh2  = (const float*)d_in[19];
    const float* bh2  = (const float*)d_in[20];
    float* out = (float*)d_out;
    float* ws  = (float*)d_ws;

    // choose largest batch chunk fitting the workspace
    int BC = 64;
    {
        const int cands[3] = {512, 256, 128};
        for (int idx = 0; idx < 3; idx++) {
            size_t need = ((size_t)86224 * cands[idx] + 206848) * 4;
            if (need <= ws_size) { BC = cands[idx]; break; }
        }
    }
    // region layout (floats): R0 = camt/out2, R1 = out1/partial, R2 = x3
    float* R0 = ws;
    float* R1 = R0 + (size_t)21168 * BC;
    float* R2 = R1 + (size_t)48672 * BC;
    float* W1t = R2 + (size_t)16384 * BC;
    float* W2t = W1t + 6144;
    float* W3t = W2t + 32768;
    float* camfeat = W3t + 36864;

    prep_weights<<<296, 256, 0, stream>>>(W1, W2, W3, W1t, W2t, W3t);
    int blk = (BC < 256) ? BC : 256;
    for (int b0 = 0; b0 < 512; b0 += BC) {
        transpose_cam<<<dim3(662, BC / 32), dim3(32, 8), 0, stream>>>(cam, R0, b0, BC);
        conv1_k<<<dim3(1521, BC / blk), blk, 0, stream>>>(R0, W1t, b1, R1, BC);
        conv2_k<<<dim3(324, BC / blk), blk, 0, stream>>>(R1, W2t, b2, R0, BC);
        conv3_k<<<dim3(256, BC / blk), blk, 0, stream>>>(R0, W3t, b3, R2, BC);
        proj_k<<<dim3(256, BC / blk), blk, 0, stream>>>(R2, Wp, R1, BC);
        reduce_k<<<BC, 256, 0, stream>>>(R1, bp, camfeat, b0, BC);
    }
    gat_head<<<512, 256, 0, stream>>>(camfeat, pos, tpos, aidx, Wg, asrc, adst,
                                      Wid, bid, Wh1, bh1, Wh2, bh2, out);
}

// Round 2
// 164.246 us; speedup vs baseline: 3.8158x; 3.8158x over previous
//
#include <hip/hip_runtime.h>

// ---------------------------------------------------------------------------
// GNNPerAgentModel — round 1: bf16 MFMA implicit-GEMM conv chain.
// Activations: batch-minor bf16 pairs  act32[k/2 * BC + b] = {k even, k odd}.
// Weights: prepacked A-fragment layout Wt32[(k8*M + oc)*4 + j2] (8 bf16 per lane).
// mfma_f32_16x16x32_bf16: A lane: row=l&15, k=8*(l>>4)+j ; B lane: col=l&15,
// k=8*(l>>4)+j ; C/D lane: col=l&15, row=4*(l>>4)+reg  (verified mapping).
// Wave tile: 64(M) x 32(N), K-step 32: 4 A-loads(dwordx4) + 8 B-loads(dword),
// 8 MFMA. No LDS in GEMM kernels.
// ---------------------------------------------------------------------------

typedef __attribute__((ext_vector_type(8))) short bf16x8;
typedef __attribute__((ext_vector_type(4))) float f32x4;

union U4 { uint4 v; unsigned int u[4]; bf16x8 h; };

__device__ __forceinline__ unsigned short f2bf(float x) {
    unsigned int u = __float_as_uint(x);
    return (unsigned short)((u + 0x7FFFu + ((u >> 16) & 1u)) >> 16);
}
__device__ __forceinline__ unsigned int pack2(float lo, float hi) {
    return (unsigned int)f2bf(lo) | ((unsigned int)f2bf(hi) << 16);
}
__device__ __forceinline__ bf16x8 loadA(const unsigned int* __restrict__ W, int k8, int M, int oc) {
    U4 r; r.v = *(const uint4*)(W + (((size_t)k8 * M + oc) << 2));
    return r.h;
}
__device__ __forceinline__ bf16x8 loadB(const unsigned int* __restrict__ p, size_t BC) {
    U4 r; r.u[0] = p[0]; r.u[1] = p[BC]; r.u[2] = p[2 * BC]; r.u[3] = p[3 * BC];
    return r.h;
}
#define MFMA(a, b, c) __builtin_amdgcn_mfma_f32_16x16x32_bf16((a), (b), (c), 0, 0, 0)

// ---------------- weight prepack (bf16, A-fragment layout) ----------------
// W1t: M=32, K=192, k = c*64 + kh*8 + kw          (24 k8-groups)
// W2t: M=64, K=512, k = (kh*4+kw)*32 + ic         (64 k8-groups)
// W3t: M=64, K=576, k = (kh*3+kw)*64 + ic         (72 k8-groups)
// Wpt: M=256, K=16384, k' = s3*64 + oc3  <-> orig row = oc3*256 + s3 (2048 k8)
__global__ __launch_bounds__(256) void prepack(
    const float* __restrict__ W1, const float* __restrict__ W2,
    const float* __restrict__ W3, const float* __restrict__ Wp,
    unsigned int* __restrict__ W1t, unsigned int* __restrict__ W2t,
    unsigned int* __restrict__ W3t, unsigned int* __restrict__ Wpt)
{
    int i = blockIdx.x * 256 + threadIdx.x;
    if (i < 3072) {                       // (k8*32+oc)*4+j2
        int j2 = i & 3, oc = (i >> 2) & 31, k8 = i >> 7;
        int c = k8 >> 3, kh = k8 & 7, kw = 2 * j2;
        const float* s = W1 + ((oc * 3 + c) * 8 + kh) * 8;
        W1t[i] = pack2(s[kw], s[kw + 1]);
    } else if (i < 3072 + 16384) {        // (k8*64+oc)*4+j2
        int j = i - 3072;
        int j2 = j & 3, oc = (j >> 2) & 63, k8 = j >> 8;
        int tap = k8 >> 2, ic = (k8 & 3) * 8 + 2 * j2;
        int kh = tap >> 2, kw = tap & 3;
        float a = W2[((oc * 32 + ic) * 4 + kh) * 4 + kw];
        float b = W2[((oc * 32 + ic + 1) * 4 + kh) * 4 + kw];
        W2t[j] = pack2(a, b);
    } else if (i < 3072 + 16384 + 18432) { // (k8*64+oc)*4+j2
        int j = i - 3072 - 16384;
        int j2 = j & 3, oc = (j >> 2) & 63, k8 = j >> 8;
        int tap = k8 >> 3, ic = (k8 & 7) * 8 + 2 * j2;
        int kh = tap / 3, kw = tap % 3;
        float a = W3[((oc * 64 + ic) * 3 + kh) * 3 + kw];
        float b = W3[((oc * 64 + ic + 1) * 3 + kh) * 3 + kw];
        W3t[j] = pack2(a, b);
    } else {                               // (k8*256+n)*4+j2
        int j = i - 3072 - 16384 - 18432;
        if (j < 2097152) {
            int j2 = j & 3, n = (j >> 2) & 255, k8 = j >> 10;
            int s3 = k8 >> 3, oc = (k8 & 7) * 8 + 2 * j2;
            float a = Wp[(size_t)(oc * 256 + s3) * 256 + n];
            float b = Wp[(size_t)((oc + 1) * 256 + s3) * 256 + n];
            Wpt[j] = pack2(a, b);
        }
    }
}

// cam [512][84][84][3] fp32 -> camt32[((c*84+y)*42 + x2)*BC + b] bf16 pairs over x
__global__ __launch_bounds__(256) void transpose_cam(
    const float* __restrict__ cam, unsigned int* __restrict__ camt, int b0, int BC)
{
    __shared__ float lds[32][253];
    int yy = blockIdx.x;
    int bb = blockIdx.y * 32;
    int t = threadIdx.x;
    for (int f = t; f < 8064; f += 256) {
        int b = f / 252, p = f - b * 252;
        lds[b][p] = cam[(size_t)(b0 + bb + b) * 21168 + yy * 252 + p];
    }
    __syncthreads();
    for (int g = t; g < 4032; g += 256) {
        int b = g & 31, q = g >> 5;
        int c = q / 42, x2 = q - c * 42;
        unsigned int v = pack2(lds[b][6 * x2 + c], lds[b][6 * x2 + 3 + c]);
        camt[(size_t)((c * 84 + yy) * 42 + x2) * BC + bb + b] = v;
    }
}

// conv1: 3ch 84x84 -> 32ch 39x39, k=8 s=2. M=32, K=192 (6 steps).
__global__ __launch_bounds__(256) void conv1_mfma(
    const unsigned int* __restrict__ in32, const unsigned int* __restrict__ Wt,
    const float* __restrict__ bias, unsigned int* __restrict__ out32, int BC)
{
    int s = blockIdx.x; int oh = s / 39, ow = s - oh * 39;
    int wv = threadIdx.x >> 6, l = threadIdx.x & 63;
    int lg = l >> 4, lc = l & 15;
    const size_t sBC = (size_t)BC;
    size_t bcol = (size_t)blockIdx.y * 128 + wv * 32 + lc;
    f32x4 acc[2][2] = {};
    int ybase = 2 * oh;
    #pragma unroll
    for (int sp = 0; sp < 3; sp++) {               // c = sp ; steps 2sp, 2sp+1
        const int s0 = 2 * sp, s1 = s0 + 1;
        bf16x8 A0[2], A1[2], B0[2], B1[2];
        #pragma unroll
        for (int m = 0; m < 2; m++) {
            A0[m] = loadA(Wt, s0 * 4 + lg, 32, m * 16 + lc);
            A1[m] = loadA(Wt, s1 * 4 + lg, 32, m * 16 + lc);
        }
        const unsigned int* p0 = in32 + (size_t)((sp * 84 + ybase + lg) * 42 + ow) * sBC + bcol;
        const unsigned int* p1 = in32 + (size_t)((sp * 84 + ybase + 4 + lg) * 42 + ow) * sBC + bcol;
        B0[0] = loadB(p0, sBC); B0[1] = loadB(p0 + 16, sBC);
        B1[0] = loadB(p1, sBC); B1[1] = loadB(p1 + 16, sBC);
        #pragma unroll
        for (int m = 0; m < 2; m++) {
            acc[m][0] = MFMA(A0[m], B0[0], acc[m][0]);
            acc[m][1] = MFMA(A0[m], B0[1], acc[m][1]);
            acc[m][0] = MFMA(A1[m], B1[0], acc[m][0]);
            acc[m][1] = MFMA(A1[m], B1[1], acc[m][1]);
        }
    }
    #pragma unroll
    for (int m = 0; m < 2; m++) {
        float4 bv = *(const float4*)(bias + m * 16 + lg * 4);
        #pragma unroll
        for (int g = 0; g < 2; g++) {
            f32x4 a = acc[m][g];
            unsigned int u0 = pack2(fmaxf(a.x + bv.x, 0.f), fmaxf(a.y + bv.y, 0.f));
            unsigned int u1 = pack2(fmaxf(a.z + bv.z, 0.f), fmaxf(a.w + bv.w, 0.f));
            size_t o = (size_t)(s * 16 + m * 8 + lg * 2) * sBC
                     + (size_t)blockIdx.y * 128 + wv * 32 + g * 16 + lc;
            out32[o] = u0; out32[o + sBC] = u1;
        }
    }
}

// conv2: 32ch 39x39 -> 64ch 18x18, k=4 s=2. M=64, K=512 (16 steps, tap=step).
__global__ __launch_bounds__(256) void conv2_mfma(
    const unsigned int* __restrict__ in32, const unsigned int* __restrict__ Wt,
    const float* __restrict__ bias, unsigned int* __restrict__ out32, int BC)
{
    int s = blockIdx.x; int oh = s / 18, ow = s - oh * 18;
    int wv = threadIdx.x >> 6, l = threadIdx.x & 63;
    int lg = l >> 4, lc = l & 15;
    const size_t sBC = (size_t)BC;
    size_t bcol = (size_t)blockIdx.y * 128 + wv * 32 + lc;
    f32x4 acc[4][2] = {};
    int ybase = 2 * oh, xbase = 2 * ow;
    #pragma unroll
    for (int sp = 0; sp < 8; sp++) {
        const int s0 = 2 * sp, s1 = s0 + 1;
        bf16x8 A0[4], A1[4], B0[2], B1[2];
        #pragma unroll
        for (int m = 0; m < 4; m++) {
            A0[m] = loadA(Wt, s0 * 4 + lg, 64, m * 16 + lc);
            A1[m] = loadA(Wt, s1 * 4 + lg, 64, m * 16 + lc);
        }
        {
            const int kh = s0 >> 2, kw = s0 & 3;
            const unsigned int* p = in32
                + (size_t)((((ybase + kh) * 39 + xbase + kw) * 16) + lg * 4) * sBC + bcol;
            B0[0] = loadB(p, sBC); B0[1] = loadB(p + 16, sBC);
        }
        {
            const int kh = s1 >> 2, kw = s1 & 3;
            const unsigned int* p = in32
                + (size_t)((((ybase + kh) * 39 + xbase + kw) * 16) + lg * 4) * sBC + bcol;
            B1[0] = loadB(p, sBC); B1[1] = loadB(p + 16, sBC);
        }
        #pragma unroll
        for (int m = 0; m < 4; m++) {
            acc[m][0] = MFMA(A0[m], B0[0], acc[m][0]);
            acc[m][1] = MFMA(A0[m], B0[1], acc[m][1]);
        }
        #pragma unroll
        for (int m = 0; m < 4; m++) {
            acc[m][0] = MFMA(A1[m], B1[0], acc[m][0]);
            acc[m][1] = MFMA(A1[m], B1[1], acc[m][1]);
        }
    }
    #pragma unroll
    for (int m = 0; m < 4; m++) {
        float4 bv = *(const float4*)(bias + m * 16 + lg * 4);
        #pragma unroll
        for (int g = 0; g < 2; g++) {
            f32x4 a = acc[m][g];
            unsigned int u0 = pack2(fmaxf(a.x + bv.x, 0.f), fmaxf(a.y + bv.y, 0.f));
            unsigned int u1 = pack2(fmaxf(a.z + bv.z, 0.f), fmaxf(a.w + bv.w, 0.f));
            size_t o = (size_t)(s * 32 + m * 8 + lg * 2) * sBC
                     + (size_t)blockIdx.y * 128 + wv * 32 + g * 16 + lc;
            out32[o] = u0; out32[o + sBC] = u1;
        }
    }
}

// conv3: 64ch 18x18 -> 64ch 16x16, k=3 s=1. M=64, K=576 (18 steps, tap=step/2).
__global__ __launch_bounds__(256) void conv3_mfma(
    const unsigned int* __restrict__ in32, const unsigned int* __restrict__ Wt,
    const float* __restrict__ bias, unsigned int* __restrict__ out32, int BC)
{
    int s = blockIdx.x; int oh = s >> 4, ow = s & 15;
    int wv = threadIdx.x >> 6, l = threadIdx.x & 63;
    int lg = l >> 4, lc = l & 15;
    const size_t sBC = (size_t)BC;
    size_t bcol = (size_t)blockIdx.y * 128 + wv * 32 + lc;
    f32x4 acc[4][2] = {};
    #pragma unroll
    for (int sp = 0; sp < 9; sp++) {               // tap = sp ; steps 2sp, 2sp+1
        const int s0 = 2 * sp, s1 = s0 + 1;
        const int kh = sp / 3, kw = sp - kh * 3;
        bf16x8 A0[4], A1[4], B0[2], B1[2];
        #pragma unroll
        for (int m = 0; m < 4; m++) {
            A0[m] = loadA(Wt, s0 * 4 + lg, 64, m * 16 + lc);
            A1[m] = loadA(Wt, s1 * 4 + lg, 64, m * 16 + lc);
        }
        const unsigned int* pb = in32
            + (size_t)((((oh + kh) * 18 + ow + kw) * 32)) * sBC;
        const unsigned int* p0 = pb + (size_t)(lg * 4) * sBC + bcol;        // ic8 = lg
        const unsigned int* p1 = pb + (size_t)((4 + lg) * 4) * sBC + bcol;  // ic8 = 4+lg
        B0[0] = loadB(p0, sBC); B0[1] = loadB(p0 + 16, sBC);
        B1[0] = loadB(p1, sBC); B1[1] = loadB(p1 + 16, sBC);
        #pragma unroll
        for (int m = 0; m < 4; m++) {
            acc[m][0] = MFMA(A0[m], B0[0], acc[m][0]);
            acc[m][1] = MFMA(A0[m], B0[1], acc[m][1]);
        }
        #pragma unroll
        for (int m = 0; m < 4; m++) {
            acc[m][0] = MFMA(A1[m], B1[0], acc[m][0]);
            acc[m][1] = MFMA(A1[m], B1[1], acc[m][1]);
        }
    }
    #pragma unroll
    for (int m = 0; m < 4; m++) {
        float4 bv = *(const float4*)(bias + m * 16 + lg * 4);
        #pragma unroll
        for (int g = 0; g < 2; g++) {
            f32x4 a = acc[m][g];
            unsigned int u0 = pack2(fmaxf(a.x + bv.x, 0.f), fmaxf(a.y + bv.y, 0.f));
            unsigned int u1 = pack2(fmaxf(a.z + bv.z, 0.f), fmaxf(a.w + bv.w, 0.f));
            size_t o = (size_t)(s * 32 + m * 8 + lg * 2) * sBC
                     + (size_t)blockIdx.y * 128 + wv * 32 + g * 16 + lc;
            out32[o] = u0; out32[o + sBC] = u1;
        }
    }
}

// proj: x3[k'][b] (K=16384, k'=s3*64+oc) @ Wpt -> partial[kseg][n][b], K-split 32
__global__ __launch_bounds__(256) void proj_mfma(
    const unsigned int* __restrict__ x3, const unsigned int* __restrict__ Wpt,
    float* __restrict__ partial, int BC)
{
    int mq = blockIdx.x;          // 0..3 : n-quarter
    int kseg = blockIdx.z;        // 0..31
    int wv = threadIdx.x >> 6, l = threadIdx.x & 63;
    int lg = l >> 4, lc = l & 15;
    const size_t sBC = (size_t)BC;
    size_t bcol = (size_t)blockIdx.y * 128 + wv * 32 + lc;
    f32x4 acc[4][2] = {};
    #pragma unroll
    for (int sp = 0; sp < 8; sp++) {               // s3 = kseg*8+sp ; steps 2sp,2sp+1
        const int s0 = 2 * sp, s1 = s0 + 1;
        const int s3 = kseg * 8 + sp;
        bf16x8 A0[4], A1[4], B0[2], B1[2];
        #pragma unroll
        for (int m = 0; m < 4; m++) {
            A0[m] = loadA(Wpt, kseg * 64 + s0 * 4 + lg, 256, mq * 64 + m * 16 + lc);
            A1[m] = loadA(Wpt, kseg * 64 + s1 * 4 + lg, 256, mq * 64 + m * 16 + lc);
        }
        const unsigned int* pb = x3 + (size_t)(s3 * 32) * sBC;
        const unsigned int* p0 = pb + (size_t)(lg * 4) * sBC + bcol;
        const unsigned int* p1 = pb + (size_t)((4 + lg) * 4) * sBC + bcol;
        B0[0] = loadB(p0, sBC); B0[1] = loadB(p0 + 16, sBC);
        B1[0] = loadB(p1, sBC); B1[1] = loadB(p1 + 16, sBC);
        #pragma unroll
        for (int m = 0; m < 4; m++) {
            acc[m][0] = MFMA(A0[m], B0[0], acc[m][0]);
            acc[m][1] = MFMA(A0[m], B0[1], acc[m][1]);
        }
        #pragma unroll
        for (int m = 0; m < 4; m++) {
            acc[m][0] = MFMA(A1[m], B1[0], acc[m][0]);
            acc[m][1] = MFMA(A1[m], B1[1], acc[m][1]);
        }
    }
    #pragma unroll
    for (int m = 0; m < 4; m++) {
        #pragma unroll
        for (int g = 0; g < 2; g++) {
            f32x4 a = acc[m][g];
            float* pp = partial
                + (size_t)(kseg * 256 + mq * 64 + m * 16 + lg * 4) * sBC
                + (size_t)blockIdx.y * 128 + wv * 32 + g * 16 + lc;
            pp[0] = a.x; pp[sBC] = a.y; pp[2 * sBC] = a.z; pp[3 * sBC] = a.w;
        }
    }
}

__global__ __launch_bounds__(256) void reduce_k(
    const float* __restrict__ partial, const float* __restrict__ bp,
    float* __restrict__ camfeat, int b0, int BC, int bcShift)
{
    int i = blockIdx.x * 256 + threadIdx.x;
    int bl = i & (BC - 1);
    int n = i >> bcShift;
    float s = 0.f;
    for (int seg = 0; seg < 32; seg++)
        s += partial[((size_t)(seg * 256 + n) << bcShift) + bl];
    camfeat[(size_t)(b0 + bl) * 256 + n] = fmaxf(s + bp[n], 0.f);
}

// GAT (agent row only) + id-embed + MLP head. One block per batch element.
__global__ __launch_bounds__(256) void gat_head(
    const float* __restrict__ camfeat, const float* __restrict__ pos,
    const float* __restrict__ tpos, const int* __restrict__ aidx,
    const float* __restrict__ Wg, const float* __restrict__ asrc, const float* __restrict__ adst,
    const float* __restrict__ Wid, const float* __restrict__ bid,
    const float* __restrict__ Wh1, const float* __restrict__ bh1,
    const float* __restrict__ Wh2, const float* __restrict__ bh2,
    float* __restrict__ out)
{
    int b = blockIdx.x, t = threadIdx.x;
    __shared__ float cf[256];
    __shared__ float hN[16][256];
    __shared__ float srcv[16][2], dstv[16][2];
    __shared__ float alpha[16][2];
    __shared__ float af[320];
    __shared__ float zz[256];
    __shared__ unsigned int adjm_s;

    int ai = aidx[b];
    cf[t] = camfeat[b * 256 + t];
    __syncthreads();

    float basev = 0.f;
    for (int k = 0; k < 256; k++) basev += cf[k] * Wg[k * 256 + t];

    float rw0 = Wg[256 * 256 + t], rw1 = Wg[257 * 256 + t], rw2 = Wg[258 * 256 + t];
    float px = pos[b * 3 + 0], py = pos[b * 3 + 1], pz = pos[b * 3 + 2];
    for (int n = 0; n < 16; n++) {
        float r0 = tpos[(b * 16 + n) * 3 + 0] - px;
        float r1 = tpos[(b * 16 + n) * 3 + 1] - py;
        float r2 = tpos[(b * 16 + n) * 3 + 2] - pz;
        hN[n][t] = basev + r0 * rw0 + r1 * rw1 + r2 * rw2;
    }

    if (t < 64) {
        bool on = false;
        if (t < 16 && t != ai) {
            float dx = tpos[(b * 16 + ai) * 3 + 0] - tpos[(b * 16 + t) * 3 + 0];
            float dy = tpos[(b * 16 + ai) * 3 + 1] - tpos[(b * 16 + t) * 3 + 1];
            float dz = tpos[(b * 16 + ai) * 3 + 2] - tpos[(b * 16 + t) * 3 + 2];
            on = (dx * dx + dy * dy + dz * dz) < 10000.0f;
        }
        unsigned long long m = __ballot(on);
        if (t == 0) adjm_s = (m == 0ull) ? (1u << ai) : (unsigned int)m;
    }
    __syncthreads();

    {
        int p = t >> 3, sub = t & 7;
        int j = p >> 1, h = p & 1;
        float s1 = 0.f, s2 = 0.f;
        #pragma unroll
        for (int dd = 0; dd < 16; dd++) {
            int d = h * 128 + sub * 16 + dd;
            float v = hN[j][d];
            s1 += v * asrc[d];
            s2 += v * adst[d];
        }
        s1 += __shfl_xor(s1, 1); s1 += __shfl_xor(s1, 2); s1 += __shfl_xor(s1, 4);
        s2 += __shfl_xor(s2, 1); s2 += __shfl_xor(s2, 2); s2 += __shfl_xor(s2, 4);
        if (sub == 0) { srcv[j][h] = s1; dstv[j][h] = s2; }
    }
    __syncthreads();

    if (t < 32) {
        int j = t & 15, h = t >> 4;
        unsigned int am = adjm_s;
        float e = srcv[ai][h] + dstv[j][h];
        e = (e > 0.f) ? e : 0.2f * e;
        e = ((am >> j) & 1u) ? e : -1e9f;
        float mx = e;
        mx = fmaxf(mx, __shfl_xor(mx, 1));
        mx = fmaxf(mx, __shfl_xor(mx, 2));
        mx = fmaxf(mx, __shfl_xor(mx, 4));
        mx = fmaxf(mx, __shfl_xor(mx, 8));
        float ex = __expf(e - mx);
        float sm = ex;
        sm += __shfl_xor(sm, 1); sm += __shfl_xor(sm, 2);
        sm += __shfl_xor(sm, 4); sm += __shfl_xor(sm, 8);
        alpha[j][h] = ex / sm;
    }
    __syncthreads();

    {
        int h = t >> 7;
        float o = 0.f;
        #pragma unroll
        for (int j = 0; j < 16; j++) o += alpha[j][h] * hN[j][t];
        o = (o > 0.f) ? o : (__expf(o) - 1.f);
        af[t] = o;
    }
    if (t < 64) {
        float v = (float)ai * Wid[t] + bid[t];
        af[256 + t] = fmaxf(v, 0.f);
    }
    __syncthreads();

    float zv = bh1[t];
    for (int k = 0; k < 320; k++) zv += af[k] * Wh1[k * 256 + t];
    zz[t] = fmaxf(zv, 0.f);
    __syncthreads();

    if (t < 6) {
        float lv = bh2[t];
        for (int k = 0; k < 256; k++) lv += zz[k] * Wh2[k * 6 + t];
        out[b * 6 + t] = lv;
    }
}

extern "C" void kernel_launch(void* const* d_in, const int* in_sizes, int n_in,
                              void* d_out, int out_size, void* d_ws, size_t ws_size,
                              hipStream_t stream)
{
    const float* cam  = (const float*)d_in[0];
    const float* pos  = (const float*)d_in[1];
    const float* tpos = (const float*)d_in[2];
    const int*   aidx = (const int*)d_in[3];
    const float* W1   = (const float*)d_in[4];
    const float* b1   = (const float*)d_in[5];
    const float* W2   = (const float*)d_in[6];
    const float* b2   = (const float*)d_in[7];
    const float* W3   = (const float*)d_in[8];
    const float* b3   = (const float*)d_in[9];
    const float* Wp   = (const float*)d_in[10];
    const float* bp   = (const float*)d_in[11];
    const float* Wid  = (const float*)d_in[12];
    const float* bid  = (const float*)d_in[13];
    const float* Wg   = (const float*)d_in[14];
    const float* asrc = (const float*)d_in[15];
    const float* adst = (const float*)d_in[16];
    const float* Wh1  = (const float*)d_in[17];
    const float* bh1  = (const float*)d_in[18];
    const float* Wh2  = (const float*)d_in[19];
    const float* bh2  = (const float*)d_in[20];
    float* out = (float*)d_out;

    // batch chunk: per-chunk u32 = 51304*BC ; fixed u32 = 2,266,112
    int BC = 128;
    {
        const int cands[3] = {512, 256, 128};
        for (int idx = 0; idx < 3; idx++) {
            size_t need = ((size_t)51304 * cands[idx] + 2266112) * 4;
            if (need <= ws_size) { BC = cands[idx]; break; }
        }
    }
    int bcShift = (BC == 512) ? 9 : (BC == 256) ? 8 : 7;

    unsigned int* ws32 = (unsigned int*)d_ws;
    unsigned int* RA  = ws32;                                  // camt (10584*BC) / out2 (10368*BC)
    unsigned int* RB  = RA + (size_t)10584 * BC;               // out1 (24336*BC)
    unsigned int* RC  = RB + (size_t)24336 * BC;               // x3   (8192*BC)
    float*        RD  = (float*)(RC + (size_t)8192 * BC);      // partial (8192*BC f32)
    unsigned int* W1t = (unsigned int*)(RD + (size_t)8192 * BC);
    unsigned int* W2t = W1t + 3072;
    unsigned int* W3t = W2t + 16384;
    unsigned int* Wpt = W3t + 18432;
    float* camfeat    = (float*)(Wpt + 2097152);               // 512*256 f32

    prepack<<<8340, 256, 0, stream>>>(W1, W2, W3, Wp, W1t, W2t, W3t, Wpt);

    for (int b0 = 0; b0 < 512; b0 += BC) {
        transpose_cam<<<dim3(84, BC / 32), 256, 0, stream>>>(cam, RA, b0, BC);
        conv1_mfma<<<dim3(1521, BC / 128), 256, 0, stream>>>(RA, W1t, b1, RB, BC);
        conv2_mfma<<<dim3(324, BC / 128), 256, 0, stream>>>(RB, W2t, b2, RA, BC);
        conv3_mfma<<<dim3(256, BC / 128), 256, 0, stream>>>(RA, W3t, b3, RC, BC);
        proj_mfma<<<dim3(4, BC / 128, 32), 256, 0, stream>>>(RC, Wpt, RD, BC);
        reduce_k<<<BC, 256, 0, stream>>>(RD, bp, camfeat, b0, BC, bcShift);
    }
    gat_head<<<512, 256, 0, stream>>>(camfeat, pos, tpos, aidx, Wg, asrc, adst,
                                      Wid, bid, Wh1, bh1, Wh2, bh2, out);
}

// Round 3
// 163.493 us; speedup vs baseline: 3.8334x; 1.0046x over previous
//
#include <hip/hip_runtime.h>

// ---------------------------------------------------------------------------
// GNNPerAgentModel — round 2.
//  * conv chain: bf16 MFMA implicit-GEMM, batch-minor bf16-pair activations,
//    now with bijective XCD swizzle (contiguous spatial range per XCD -> L2
//    captures tap re-reads).
//  * GAT/head: dense matmuls hoisted to batched MFMA GEMMs (weights read once):
//      gat_prep:  hNbase = camfeat @ Wg[:256]   (M=256,K=256,N=512)
//      gat_mid:   per-batch rel-pos + attention + gather (light)
//      head_mfma: z = relu(af @ Wh1 + bh1)      (M=256,K=320,N=512)
//      logits_k:  out = z @ Wh2 + bh2
// ---------------------------------------------------------------------------

typedef __attribute__((ext_vector_type(8))) short bf16x8;
typedef __attribute__((ext_vector_type(4))) float f32x4;

union U4 { uint4 v; unsigned int u[4]; bf16x8 h; };

__device__ __forceinline__ unsigned short f2bf(float x) {
    unsigned int u = __float_as_uint(x);
    return (unsigned short)((u + 0x7FFFu + ((u >> 16) & 1u)) >> 16);
}
__device__ __forceinline__ unsigned int pack2(float lo, float hi) {
    return (unsigned int)f2bf(lo) | ((unsigned int)f2bf(hi) << 16);
}
__device__ __forceinline__ bf16x8 loadA(const unsigned int* __restrict__ W, int k8, int M, int oc) {
    U4 r; r.v = *(const uint4*)(W + (((size_t)k8 * M + oc) << 2));
    return r.h;
}
__device__ __forceinline__ bf16x8 loadB(const unsigned int* __restrict__ p, size_t BC) {
    U4 r; r.u[0] = p[0]; r.u[1] = p[BC]; r.u[2] = p[2 * BC]; r.u[3] = p[3 * BC];
    return r.h;
}
#define MFMA(a, b, c) __builtin_amdgcn_mfma_f32_16x16x32_bf16((a), (b), (c), 0, 0, 0)

// bijective XCD swizzle (m204): round-robin L -> contiguous work ranges per XCD
__device__ __forceinline__ int xcd_swz(int L, int nwg) {
    int q = nwg >> 3, r = nwg & 7;
    int x = L & 7, i = L >> 3;
    return (x < r ? x * (q + 1) : r * (q + 1) + (x - r) * q) + i;
}

// ---------------- weight prepack (bf16, A-fragment layout) ----------------
// W1t: M=32,  K=192   k = c*64 + kh*8 + kw        (24 k8)   3072 u32
// W2t: M=64,  K=512   k = (kh*4+kw)*32 + ic       (64 k8)   16384 u32
// W3t: M=64,  K=576   k = (kh*3+kw)*64 + ic       (72 k8)   18432 u32
// Wpt: M=256, K=16384 k' = s3*64 + oc3            (2048 k8) 2097152 u32
// Wgt: M=256, K=256   k = input col               (32 k8)   32768 u32
// Wh1t:M=256, K=320   k = input col               (40 k8)   40960 u32
__global__ __launch_bounds__(256) void prepack(
    const float* __restrict__ W1, const float* __restrict__ W2,
    const float* __restrict__ W3, const float* __restrict__ Wp,
    const float* __restrict__ Wg, const float* __restrict__ Wh1,
    unsigned int* __restrict__ W1t, unsigned int* __restrict__ W2t,
    unsigned int* __restrict__ W3t, unsigned int* __restrict__ Wpt,
    unsigned int* __restrict__ Wgt, unsigned int* __restrict__ Wh1t)
{
    int i = blockIdx.x * 256 + threadIdx.x;
    if (i < 3072) {
        int j2 = i & 3, oc = (i >> 2) & 31, k8 = i >> 7;
        int c = k8 >> 3, kh = k8 & 7, kw = 2 * j2;
        const float* s = W1 + ((oc * 3 + c) * 8 + kh) * 8;
        W1t[i] = pack2(s[kw], s[kw + 1]);
    } else if (i < 19456) {
        int j = i - 3072;
        int j2 = j & 3, oc = (j >> 2) & 63, k8 = j >> 8;
        int tap = k8 >> 2, ic = (k8 & 3) * 8 + 2 * j2;
        int kh = tap >> 2, kw = tap & 3;
        float a = W2[((oc * 32 + ic) * 4 + kh) * 4 + kw];
        float b = W2[((oc * 32 + ic + 1) * 4 + kh) * 4 + kw];
        W2t[j] = pack2(a, b);
    } else if (i < 37888) {
        int j = i - 19456;
        int j2 = j & 3, oc = (j >> 2) & 63, k8 = j >> 8;
        int tap = k8 >> 3, ic = (k8 & 7) * 8 + 2 * j2;
        int kh = tap / 3, kw = tap % 3;
        float a = W3[((oc * 64 + ic) * 3 + kh) * 3 + kw];
        float b = W3[((oc * 64 + ic + 1) * 3 + kh) * 3 + kw];
        W3t[j] = pack2(a, b);
    } else if (i < 2135040) {
        int j = i - 37888;
        int j2 = j & 3, n = (j >> 2) & 255, k8 = j >> 10;
        int s3 = k8 >> 3, oc = (k8 & 7) * 8 + 2 * j2;
        float a = Wp[(size_t)(oc * 256 + s3) * 256 + n];
        float b = Wp[(size_t)((oc + 1) * 256 + s3) * 256 + n];
        Wpt[j] = pack2(a, b);
    } else if (i < 2167808) {
        int j = i - 2135040;
        int j2 = j & 3, m = (j >> 2) & 255, k8 = j >> 10;
        int k = k8 * 8 + 2 * j2;
        Wgt[j] = pack2(Wg[k * 256 + m], Wg[(k + 1) * 256 + m]);
    } else if (i < 2208768) {
        int j = i - 2167808;
        int j2 = j & 3, m = (j >> 2) & 255, k8 = j >> 10;
        int k = k8 * 8 + 2 * j2;
        Wh1t[j] = pack2(Wh1[k * 256 + m], Wh1[(k + 1) * 256 + m]);
    }
}

// cam [512][84][84][3] fp32 -> camt32[((c*84+y)*42 + x2)*BC + b] bf16 pairs over x
__global__ __launch_bounds__(256) void transpose_cam(
    const float* __restrict__ cam, unsigned int* __restrict__ camt, int b0, int BC)
{
    __shared__ float lds[32][253];
    int yy = blockIdx.x;
    int bb = blockIdx.y * 32;
    int t = threadIdx.x;
    for (int f = t; f < 8064; f += 256) {
        int b = f / 252, p = f - b * 252;
        lds[b][p] = cam[(size_t)(b0 + bb + b) * 21168 + yy * 252 + p];
    }
    __syncthreads();
    for (int g = t; g < 4032; g += 256) {
        int b = g & 31, q = g >> 5;
        int c = q / 42, x2 = q - c * 42;
        unsigned int v = pack2(lds[b][6 * x2 + c], lds[b][6 * x2 + 3 + c]);
        camt[(size_t)((c * 84 + yy) * 42 + x2) * BC + bb + b] = v;
    }
}

// conv1: 3ch 84x84 -> 32ch 39x39, k=8 s=2. M=32, K=192 (6 steps).
__global__ __launch_bounds__(256) void conv1_mfma(
    const unsigned int* __restrict__ in32, const unsigned int* __restrict__ Wt,
    const float* __restrict__ bias, unsigned int* __restrict__ out32, int BC, int bqShift)
{
    int wgid = xcd_swz(blockIdx.x, gridDim.x);
    int bq = wgid & ((1 << bqShift) - 1);
    int s = wgid >> bqShift;
    int oh = s / 39, ow = s - oh * 39;
    int wv = threadIdx.x >> 6, l = threadIdx.x & 63;
    int lg = l >> 4, lc = l & 15;
    const size_t sBC = (size_t)BC;
    size_t bcol = (size_t)bq * 128 + wv * 32 + lc;
    f32x4 acc[2][2] = {};
    int ybase = 2 * oh;
    #pragma unroll
    for (int sp = 0; sp < 3; sp++) {
        const int s0 = 2 * sp, s1 = s0 + 1;
        bf16x8 A0[2], A1[2], B0[2], B1[2];
        #pragma unroll
        for (int m = 0; m < 2; m++) {
            A0[m] = loadA(Wt, s0 * 4 + lg, 32, m * 16 + lc);
            A1[m] = loadA(Wt, s1 * 4 + lg, 32, m * 16 + lc);
        }
        const unsigned int* p0 = in32 + (size_t)((sp * 84 + ybase + lg) * 42 + ow) * sBC + bcol;
        const unsigned int* p1 = in32 + (size_t)((sp * 84 + ybase + 4 + lg) * 42 + ow) * sBC + bcol;
        B0[0] = loadB(p0, sBC); B0[1] = loadB(p0 + 16, sBC);
        B1[0] = loadB(p1, sBC); B1[1] = loadB(p1 + 16, sBC);
        #pragma unroll
        for (int m = 0; m < 2; m++) {
            acc[m][0] = MFMA(A0[m], B0[0], acc[m][0]);
            acc[m][1] = MFMA(A0[m], B0[1], acc[m][1]);
            acc[m][0] = MFMA(A1[m], B1[0], acc[m][0]);
            acc[m][1] = MFMA(A1[m], B1[1], acc[m][1]);
        }
    }
    #pragma unroll
    for (int m = 0; m < 2; m++) {
        float4 bv = *(const float4*)(bias + m * 16 + lg * 4);
        #pragma unroll
        for (int g = 0; g < 2; g++) {
            f32x4 a = acc[m][g];
            unsigned int u0 = pack2(fmaxf(a.x + bv.x, 0.f), fmaxf(a.y + bv.y, 0.f));
            unsigned int u1 = pack2(fmaxf(a.z + bv.z, 0.f), fmaxf(a.w + bv.w, 0.f));
            size_t o = (size_t)(s * 16 + m * 8 + lg * 2) * sBC
                     + (size_t)bq * 128 + wv * 32 + g * 16 + lc;
            out32[o] = u0; out32[o + sBC] = u1;
        }
    }
}

// conv2: 32ch 39x39 -> 64ch 18x18, k=4 s=2. M=64, K=512 (16 steps).
__global__ __launch_bounds__(256) void conv2_mfma(
    const unsigned int* __restrict__ in32, const unsigned int* __restrict__ Wt,
    const float* __restrict__ bias, unsigned int* __restrict__ out32, int BC, int bqShift)
{
    int wgid = xcd_swz(blockIdx.x, gridDim.x);
    int bq = wgid & ((1 << bqShift) - 1);
    int s = wgid >> bqShift;
    int oh = s / 18, ow = s - oh * 18;
    int wv = threadIdx.x >> 6, l = threadIdx.x & 63;
    int lg = l >> 4, lc = l & 15;
    const size_t sBC = (size_t)BC;
    size_t bcol = (size_t)bq * 128 + wv * 32 + lc;
    f32x4 acc[4][2] = {};
    int ybase = 2 * oh, xbase = 2 * ow;
    #pragma unroll
    for (int sp = 0; sp < 8; sp++) {
        const int s0 = 2 * sp, s1 = s0 + 1;
        bf16x8 A0[4], A1[4], B0[2], B1[2];
        #pragma unroll
        for (int m = 0; m < 4; m++) {
            A0[m] = loadA(Wt, s0 * 4 + lg, 64, m * 16 + lc);
            A1[m] = loadA(Wt, s1 * 4 + lg, 64, m * 16 + lc);
        }
        {
            const int kh = s0 >> 2, kw = s0 & 3;
            const unsigned int* p = in32
                + (size_t)((((ybase + kh) * 39 + xbase + kw) * 16) + lg * 4) * sBC + bcol;
            B0[0] = loadB(p, sBC); B0[1] = loadB(p + 16, sBC);
        }
        {
            const int kh = s1 >> 2, kw = s1 & 3;
            const unsigned int* p = in32
                + (size_t)((((ybase + kh) * 39 + xbase + kw) * 16) + lg * 4) * sBC + bcol;
            B1[0] = loadB(p, sBC); B1[1] = loadB(p + 16, sBC);
        }
        #pragma unroll
        for (int m = 0; m < 4; m++) {
            acc[m][0] = MFMA(A0[m], B0[0], acc[m][0]);
            acc[m][1] = MFMA(A0[m], B0[1], acc[m][1]);
        }
        #pragma unroll
        for (int m = 0; m < 4; m++) {
            acc[m][0] = MFMA(A1[m], B1[0], acc[m][0]);
            acc[m][1] = MFMA(A1[m], B1[1], acc[m][1]);
        }
    }
    #pragma unroll
    for (int m = 0; m < 4; m++) {
        float4 bv = *(const float4*)(bias + m * 16 + lg * 4);
        #pragma unroll
        for (int g = 0; g < 2; g++) {
            f32x4 a = acc[m][g];
            unsigned int u0 = pack2(fmaxf(a.x + bv.x, 0.f), fmaxf(a.y + bv.y, 0.f));
            unsigned int u1 = pack2(fmaxf(a.z + bv.z, 0.f), fmaxf(a.w + bv.w, 0.f));
            size_t o = (size_t)(s * 32 + m * 8 + lg * 2) * sBC
                     + (size_t)bq * 128 + wv * 32 + g * 16 + lc;
            out32[o] = u0; out32[o + sBC] = u1;
        }
    }
}

// conv3: 64ch 18x18 -> 64ch 16x16, k=3 s=1. M=64, K=576 (18 steps).
__global__ __launch_bounds__(256) void conv3_mfma(
    const unsigned int* __restrict__ in32, const unsigned int* __restrict__ Wt,
    const float* __restrict__ bias, unsigned int* __restrict__ out32, int BC, int bqShift)
{
    int wgid = xcd_swz(blockIdx.x, gridDim.x);
    int bq = wgid & ((1 << bqShift) - 1);
    int s = wgid >> bqShift;
    int oh = s >> 4, ow = s & 15;
    int wv = threadIdx.x >> 6, l = threadIdx.x & 63;
    int lg = l >> 4, lc = l & 15;
    const size_t sBC = (size_t)BC;
    size_t bcol = (size_t)bq * 128 + wv * 32 + lc;
    f32x4 acc[4][2] = {};
    #pragma unroll
    for (int sp = 0; sp < 9; sp++) {
        const int s0 = 2 * sp, s1 = s0 + 1;
        const int kh = sp / 3, kw = sp - kh * 3;
        bf16x8 A0[4], A1[4], B0[2], B1[2];
        #pragma unroll
        for (int m = 0; m < 4; m++) {
            A0[m] = loadA(Wt, s0 * 4 + lg, 64, m * 16 + lc);
            A1[m] = loadA(Wt, s1 * 4 + lg, 64, m * 16 + lc);
        }
        const unsigned int* pb = in32 + (size_t)((((oh + kh) * 18 + ow + kw) * 32)) * sBC;
        const unsigned int* p0 = pb + (size_t)(lg * 4) * sBC + bcol;
        const unsigned int* p1 = pb + (size_t)((4 + lg) * 4) * sBC + bcol;
        B0[0] = loadB(p0, sBC); B0[1] = loadB(p0 + 16, sBC);
        B1[0] = loadB(p1, sBC); B1[1] = loadB(p1 + 16, sBC);
        #pragma unroll
        for (int m = 0; m < 4; m++) {
            acc[m][0] = MFMA(A0[m], B0[0], acc[m][0]);
            acc[m][1] = MFMA(A0[m], B0[1], acc[m][1]);
        }
        #pragma unroll
        for (int m = 0; m < 4; m++) {
            acc[m][0] = MFMA(A1[m], B1[0], acc[m][0]);
            acc[m][1] = MFMA(A1[m], B1[1], acc[m][1]);
        }
    }
    #pragma unroll
    for (int m = 0; m < 4; m++) {
        float4 bv = *(const float4*)(bias + m * 16 + lg * 4);
        #pragma unroll
        for (int g = 0; g < 2; g++) {
            f32x4 a = acc[m][g];
            unsigned int u0 = pack2(fmaxf(a.x + bv.x, 0.f), fmaxf(a.y + bv.y, 0.f));
            unsigned int u1 = pack2(fmaxf(a.z + bv.z, 0.f), fmaxf(a.w + bv.w, 0.f));
            size_t o = (size_t)(s * 32 + m * 8 + lg * 2) * sBC
                     + (size_t)bq * 128 + wv * 32 + g * 16 + lc;
            out32[o] = u0; out32[o + sBC] = u1;
        }
    }
}

// proj: x3[k'][b] (K=16384) @ Wpt -> partial[kseg][n][b], K-split 32
__global__ __launch_bounds__(256) void proj_mfma(
    const unsigned int* __restrict__ x3, const unsigned int* __restrict__ Wpt,
    float* __restrict__ partial, int BC, int bqShift)
{
    int wgid = xcd_swz(blockIdx.x, gridDim.x);
    int bq = wgid & ((1 << bqShift) - 1);
    int rem = wgid >> bqShift;
    int mq = rem & 3;
    int kseg = rem >> 2;
    int wv = threadIdx.x >> 6, l = threadIdx.x & 63;
    int lg = l >> 4, lc = l & 15;
    const size_t sBC = (size_t)BC;
    size_t bcol = (size_t)bq * 128 + wv * 32 + lc;
    f32x4 acc[4][2] = {};
    #pragma unroll
    for (int sp = 0; sp < 8; sp++) {
        const int s0 = 2 * sp, s1 = s0 + 1;
        const int s3 = kseg * 8 + sp;
        bf16x8 A0[4], A1[4], B0[2], B1[2];
        #pragma unroll
        for (int m = 0; m < 4; m++) {
            A0[m] = loadA(Wpt, kseg * 64 + s0 * 4 + lg, 256, mq * 64 + m * 16 + lc);
            A1[m] = loadA(Wpt, kseg * 64 + s1 * 4 + lg, 256, mq * 64 + m * 16 + lc);
        }
        const unsigned int* pb = x3 + (size_t)(s3 * 32) * sBC;
        const unsigned int* p0 = pb + (size_t)(lg * 4) * sBC + bcol;
        const unsigned int* p1 = pb + (size_t)((4 + lg) * 4) * sBC + bcol;
        B0[0] = loadB(p0, sBC); B0[1] = loadB(p0 + 16, sBC);
        B1[0] = loadB(p1, sBC); B1[1] = loadB(p1 + 16, sBC);
        #pragma unroll
        for (int m = 0; m < 4; m++) {
            acc[m][0] = MFMA(A0[m], B0[0], acc[m][0]);
            acc[m][1] = MFMA(A0[m], B0[1], acc[m][1]);
        }
        #pragma unroll
        for (int m = 0; m < 4; m++) {
            acc[m][0] = MFMA(A1[m], B1[0], acc[m][0]);
            acc[m][1] = MFMA(A1[m], B1[1], acc[m][1]);
        }
    }
    #pragma unroll
    for (int m = 0; m < 4; m++) {
        #pragma unroll
        for (int g = 0; g < 2; g++) {
            f32x4 a = acc[m][g];
            float* pp = partial
                + (size_t)(kseg * 256 + mq * 64 + m * 16 + lg * 4) * sBC
                + (size_t)bq * 128 + wv * 32 + g * 16 + lc;
            pp[0] = a.x; pp[sBC] = a.y; pp[2 * sBC] = a.z; pp[3 * sBC] = a.w;
        }
    }
}

// reduce K-split partials + bias + relu -> cf16 (bf16 pairs, batch-minor over full B=512)
__global__ __launch_bounds__(256) void reduce_k(
    const float* __restrict__ partial, const float* __restrict__ bp,
    unsigned int* __restrict__ cf16, int b0, int BC, int bcShift)
{
    int i = blockIdx.x * 256 + threadIdx.x;
    int bl = i & (BC - 1);
    int q = i >> bcShift;                       // 0..127 (pair of output cols)
    float s0 = 0.f, s1 = 0.f;
    int n0 = 2 * q;
    for (int seg = 0; seg < 32; seg++) {
        s0 += partial[((size_t)(seg * 256 + n0) << bcShift) + bl];
        s1 += partial[((size_t)(seg * 256 + n0 + 1) << bcShift) + bl];
    }
    float v0 = fmaxf(s0 + bp[n0], 0.f);
    float v1 = fmaxf(s1 + bp[n0 + 1], 0.f);
    cf16[(size_t)q * 512 + b0 + bl] = pack2(v0, v1);
}

// gat_prep: hNb[b][256] = camfeat @ Wg[:256]  (M=256,K=256,N=512). 1-wave blocks.
__global__ __launch_bounds__(64) void gat_prep(
    const unsigned int* __restrict__ cf16, const unsigned int* __restrict__ Wgt,
    float* __restrict__ hNb)
{
    int mq = blockIdx.x, bq = blockIdx.y;
    int l = threadIdx.x, lg = l >> 4, lc = l & 15;
    size_t bcol = (size_t)bq * 32 + lc;
    f32x4 acc[4][2] = {};
    #pragma unroll
    for (int sp = 0; sp < 4; sp++) {
        const int s0 = 2 * sp, s1 = s0 + 1;
        bf16x8 A0[4], A1[4], B0[2], B1[2];
        #pragma unroll
        for (int m = 0; m < 4; m++) {
            A0[m] = loadA(Wgt, s0 * 4 + lg, 256, mq * 64 + m * 16 + lc);
            A1[m] = loadA(Wgt, s1 * 4 + lg, 256, mq * 64 + m * 16 + lc);
        }
        const unsigned int* p0 = cf16 + (size_t)(sp * 32 + lg * 4) * 512 + bcol;
        const unsigned int* p1 = p0 + (size_t)16 * 512;
        B0[0] = loadB(p0, 512); B0[1] = loadB(p0 + 16, 512);
        B1[0] = loadB(p1, 512); B1[1] = loadB(p1 + 16, 512);
        #pragma unroll
        for (int m = 0; m < 4; m++) {
            acc[m][0] = MFMA(A0[m], B0[0], acc[m][0]);
            acc[m][1] = MFMA(A0[m], B0[1], acc[m][1]);
        }
        #pragma unroll
        for (int m = 0; m < 4; m++) {
            acc[m][0] = MFMA(A1[m], B1[0], acc[m][0]);
            acc[m][1] = MFMA(A1[m], B1[1], acc[m][1]);
        }
    }
    #pragma unroll
    for (int m = 0; m < 4; m++) {
        #pragma unroll
        for (int g = 0; g < 2; g++) {
            size_t b = (size_t)bq * 32 + g * 16 + lc;
            int row0 = mq * 64 + m * 16 + lg * 4;
            *(f32x4*)(hNb + b * 256 + row0) = acc[m][g];
        }
    }
}

// gat_mid: per-batch attention row + agent gather + id emb -> af16 (bf16 pairs)
__global__ __launch_bounds__(256) void gat_mid(
    const float* __restrict__ hNb, const float* __restrict__ pos,
    const float* __restrict__ tpos, const int* __restrict__ aidx,
    const float* __restrict__ Wg, const float* __restrict__ asrc, const float* __restrict__ adst,
    const float* __restrict__ Wid, const float* __restrict__ bid,
    unsigned int* __restrict__ af16)
{
    int b = blockIdx.x, t = threadIdx.x;
    __shared__ float hN[16][256];
    __shared__ float srcv[16][2], dstv[16][2];
    __shared__ float alpha[16][2];
    __shared__ float af[320];
    __shared__ unsigned int adjm_s;

    int ai = aidx[b];
    float basev = hNb[(size_t)b * 256 + t];
    float rw0 = Wg[65536 + t], rw1 = Wg[65792 + t], rw2 = Wg[66048 + t];
    float px = pos[b * 3 + 0], py = pos[b * 3 + 1], pz = pos[b * 3 + 2];
    for (int n = 0; n < 16; n++) {
        float r0 = tpos[(b * 16 + n) * 3 + 0] - px;
        float r1 = tpos[(b * 16 + n) * 3 + 1] - py;
        float r2 = tpos[(b * 16 + n) * 3 + 2] - pz;
        hN[n][t] = basev + r0 * rw0 + r1 * rw1 + r2 * rw2;
    }

    if (t < 64) {
        bool on = false;
        if (t < 16 && t != ai) {
            float dx = tpos[(b * 16 + ai) * 3 + 0] - tpos[(b * 16 + t) * 3 + 0];
            float dy = tpos[(b * 16 + ai) * 3 + 1] - tpos[(b * 16 + t) * 3 + 1];
            float dz = tpos[(b * 16 + ai) * 3 + 2] - tpos[(b * 16 + t) * 3 + 2];
            on = (dx * dx + dy * dy + dz * dz) < 10000.0f;
        }
        unsigned long long m = __ballot(on);
        if (t == 0) adjm_s = (m == 0ull) ? (1u << ai) : (unsigned int)m;
    }
    __syncthreads();

    {
        int p = t >> 3, sub = t & 7;
        int j = p >> 1, h = p & 1;
        float s1 = 0.f, s2 = 0.f;
        #pragma unroll
        for (int dd = 0; dd < 16; dd++) {
            int d = h * 128 + sub * 16 + dd;
            float v = hN[j][d];
            s1 += v * asrc[d];
            s2 += v * adst[d];
        }
        s1 += __shfl_xor(s1, 1); s1 += __shfl_xor(s1, 2); s1 += __shfl_xor(s1, 4);
        s2 += __shfl_xor(s2, 1); s2 += __shfl_xor(s2, 2); s2 += __shfl_xor(s2, 4);
        if (sub == 0) { srcv[j][h] = s1; dstv[j][h] = s2; }
    }
    __syncthreads();

    if (t < 32) {
        int j = t & 15, h = t >> 4;
        unsigned int am = adjm_s;
        float e = srcv[ai][h] + dstv[j][h];
        e = (e > 0.f) ? e : 0.2f * e;
        e = ((am >> j) & 1u) ? e : -1e9f;
        float mx = e;
        mx = fmaxf(mx, __shfl_xor(mx, 1));
        mx = fmaxf(mx, __shfl_xor(mx, 2));
        mx = fmaxf(mx, __shfl_xor(mx, 4));
        mx = fmaxf(mx, __shfl_xor(mx, 8));
        float ex = __expf(e - mx);
        float sm = ex;
        sm += __shfl_xor(sm, 1); sm += __shfl_xor(sm, 2);
        sm += __shfl_xor(sm, 4); sm += __shfl_xor(sm, 8);
        alpha[j][h] = ex / sm;
    }
    __syncthreads();

    {
        int h = t >> 7;
        float o = 0.f;
        #pragma unroll
        for (int j = 0; j < 16; j++) o += alpha[j][h] * hN[j][t];
        o = (o > 0.f) ? o : (__expf(o) - 1.f);
        af[t] = o;
    }
    if (t < 64) {
        float v = (float)ai * Wid[t] + bid[t];
        af[256 + t] = fmaxf(v, 0.f);
    }
    __syncthreads();

    if (t < 160) af16[(size_t)t * 512 + b] = pack2(af[2 * t], af[2 * t + 1]);
}

// head_mfma: zf[col][b] = relu(af @ Wh1 + bh1)  (M=256,K=320,N=512). 1-wave blocks.
__global__ __launch_bounds__(64) void head_mfma(
    const unsigned int* __restrict__ af16, const unsigned int* __restrict__ Wh1t,
    const float* __restrict__ bh1, float* __restrict__ zf)
{
    int mq = blockIdx.x, bq = blockIdx.y;
    int l = threadIdx.x, lg = l >> 4, lc = l & 15;
    size_t bcol = (size_t)bq * 32 + lc;
    f32x4 acc[4][2] = {};
    #pragma unroll
    for (int sp = 0; sp < 5; sp++) {
        const int s0 = 2 * sp, s1 = s0 + 1;
        bf16x8 A0[4], A1[4], B0[2], B1[2];
        #pragma unroll
        for (int m = 0; m < 4; m++) {
            A0[m] = loadA(Wh1t, s0 * 4 + lg, 256, mq * 64 + m * 16 + lc);
            A1[m] = loadA(Wh1t, s1 * 4 + lg, 256, mq * 64 + m * 16 + lc);
        }
        const unsigned int* p0 = af16 + (size_t)(sp * 32 + lg * 4) * 512 + bcol;
        const unsigned int* p1 = p0 + (size_t)16 * 512;
        B0[0] = loadB(p0, 512); B0[1] = loadB(p0 + 16, 512);
        B1[0] = loadB(p1, 512); B1[1] = loadB(p1 + 16, 512);
        #pragma unroll
        for (int m = 0; m < 4; m++) {
            acc[m][0] = MFMA(A0[m], B0[0], acc[m][0]);
            acc[m][1] = MFMA(A0[m], B0[1], acc[m][1]);
        }
        #pragma unroll
        for (int m = 0; m < 4; m++) {
            acc[m][0] = MFMA(A1[m], B1[0], acc[m][0]);
            acc[m][1] = MFMA(A1[m], B1[1], acc[m][1]);
        }
    }
    #pragma unroll
    for (int m = 0; m < 4; m++) {
        int row0 = mq * 64 + m * 16 + lg * 4;
        float4 bv = *(const float4*)(bh1 + row0);
        #pragma unroll
        for (int g = 0; g < 2; g++) {
            f32x4 a = acc[m][g];
            size_t b = (size_t)bq * 32 + g * 16 + lc;
            float* pp = zf + (size_t)row0 * 512 + b;
            pp[0]        = fmaxf(a.x + bv.x, 0.f);
            pp[512]      = fmaxf(a.y + bv.y, 0.f);
            pp[2 * 512]  = fmaxf(a.z + bv.z, 0.f);
            pp[3 * 512]  = fmaxf(a.w + bv.w, 0.f);
        }
    }
}

// logits: out[b][6] = zf[:,b] @ Wh2 + bh2
__global__ __launch_bounds__(256) void logits_k(
    const float* __restrict__ zf, const float* __restrict__ Wh2,
    const float* __restrict__ bh2, float* __restrict__ out)
{
    __shared__ float Ws[1536];
    int t = threadIdx.x;
    int b = blockIdx.x * 256 + t;
    for (int f = t; f < 1536; f += 256) Ws[f] = Wh2[f];
    __syncthreads();
    float acc[6];
    #pragma unroll
    for (int j = 0; j < 6; j++) acc[j] = bh2[j];
    for (int k = 0; k < 256; k++) {
        float zv = zf[(size_t)k * 512 + b];
        #pragma unroll
        for (int j = 0; j < 6; j++) acc[j] += zv * Ws[k * 6 + j];
    }
    #pragma unroll
    for (int j = 0; j < 6; j++) out[b * 6 + j] = acc[j];
}

extern "C" void kernel_launch(void* const* d_in, const int* in_sizes, int n_in,
                              void* d_out, int out_size, void* d_ws, size_t ws_size,
                              hipStream_t stream)
{
    const float* cam  = (const float*)d_in[0];
    const float* pos  = (const float*)d_in[1];
    const float* tpos = (const float*)d_in[2];
    const int*   aidx = (const int*)d_in[3];
    const float* W1   = (const float*)d_in[4];
    const float* b1   = (const float*)d_in[5];
    const float* W2   = (const float*)d_in[6];
    const float* b2   = (const float*)d_in[7];
    const float* W3   = (const float*)d_in[8];
    const float* b3   = (const float*)d_in[9];
    const float* Wp   = (const float*)d_in[10];
    const float* bp   = (const float*)d_in[11];
    const float* Wid  = (const float*)d_in[12];
    const float* bid  = (const float*)d_in[13];
    const float* Wg   = (const float*)d_in[14];
    const float* asrc = (const float*)d_in[15];
    const float* adst = (const float*)d_in[16];
    const float* Wh1  = (const float*)d_in[17];
    const float* bh1  = (const float*)d_in[18];
    const float* Wh2  = (const float*)d_in[19];
    const float* bh2  = (const float*)d_in[20];
    float* out = (float*)d_out;

    // per-chunk u32 = 51304*BC ; fixed u32 = 2,618,368
    int BC = 128;
    {
        const int cands[3] = {512, 256, 128};
        for (int idx = 0; idx < 3; idx++) {
            size_t need = ((size_t)51304 * cands[idx] + 2618368) * 4;
            if (need <= ws_size) { BC = cands[idx]; break; }
        }
    }
    int bcShift = (BC == 512) ? 9 : (BC == 256) ? 8 : 7;
    int nbq = BC >> 7;                          // batch 128-groups per chunk
    int bqShift = (BC == 512) ? 2 : (BC == 256) ? 1 : 0;

    unsigned int* ws32 = (unsigned int*)d_ws;
    unsigned int* RA  = ws32;                                  // camt / out2
    unsigned int* RB  = RA + (size_t)10584 * BC;               // out1
    unsigned int* RC  = RB + (size_t)24336 * BC;               // x3
    float*        RD  = (float*)(RC + (size_t)8192 * BC);      // partial
    unsigned int* W1t = (unsigned int*)(RD + (size_t)8192 * BC);
    unsigned int* W2t  = W1t + 3072;
    unsigned int* W3t  = W2t + 16384;
    unsigned int* Wpt  = W3t + 18432;
    unsigned int* Wgt  = Wpt + 2097152;
    unsigned int* Wh1t = Wgt + 32768;
    unsigned int* cf16 = Wh1t + 40960;                         // 128 x 512
    float*        hNb  = (float*)(cf16 + 65536);               // 512 x 256
    unsigned int* af16 = (unsigned int*)(hNb + 131072);        // 160 x 512
    float*        zf   = (float*)(af16 + 81920);               // 256 x 512

    prepack<<<8628, 256, 0, stream>>>(W1, W2, W3, Wp, Wg, Wh1,
                                      W1t, W2t, W3t, Wpt, Wgt, Wh1t);

    for (int b0 = 0; b0 < 512; b0 += BC) {
        transpose_cam<<<dim3(84, BC / 32), 256, 0, stream>>>(cam, RA, b0, BC);
        conv1_mfma<<<1521 * nbq, 256, 0, stream>>>(RA, W1t, b1, RB, BC, bqShift);
        conv2_mfma<<<324 * nbq, 256, 0, stream>>>(RB, W2t, b2, RA, BC, bqShift);
        conv3_mfma<<<256 * nbq, 256, 0, stream>>>(RA, W3t, b3, RC, BC, bqShift);
        proj_mfma<<<128 * nbq, 256, 0, stream>>>(RC, Wpt, RD, BC, bqShift);
        reduce_k<<<BC / 2, 256, 0, stream>>>(RD, bp, cf16, b0, BC, bcShift);
    }
    gat_prep<<<dim3(4, 16), 64, 0, stream>>>(cf16, Wgt, hNb);
    gat_mid<<<512, 256, 0, stream>>>(hNb, pos, tpos, aidx, Wg, asrc, adst,
                                     Wid, bid, af16);
    head_mfma<<<dim3(4, 16), 64, 0, stream>>>(af16, Wh1t, bh1, zf);
    logits_k<<<2, 256, 0, stream>>>(zf, Wh2, bh2, out);
}

// Round 4
// 147.577 us; speedup vs baseline: 4.2468x; 1.1079x over previous
//
#include <hip/hip_runtime.h>

// ---------------------------------------------------------------------------
// GNNPerAgentModel — round 4.
// Conv chain as bf16 MFMA implicit-GEMM with K-PANEL activations:
//   act[k8][b] = uint4 holding 8 consecutive k as bf16  -> B fragment is ONE
//   global_load_dwordx4. Wave tile M(32|64) x N=64 (acc[.][4]); per K-step
//   conv2/3/proj: 8 A-dwordx4 + 8 B-dwordx4 + 32 MFMA.
// Epilogues write the next layer's k-panel directly (uint2 per lane; a wave's
// 64 lanes tile 2 dense 256B rows).
// XCD swizzle: spatial in LOW bits (per-XCD chunk = one batch group,
// contiguous spatial) -> L2-resident tap re-reads.
// ---------------------------------------------------------------------------

typedef __attribute__((ext_vector_type(8))) short bf16x8;
typedef __attribute__((ext_vector_type(4))) float f32x4;

union U4 { uint4 v; unsigned int u[4]; bf16x8 h; };

__device__ __forceinline__ unsigned short f2bf(float x) {
    unsigned int u = __float_as_uint(x);
    return (unsigned short)((u + 0x7FFFu + ((u >> 16) & 1u)) >> 16);
}
__device__ __forceinline__ unsigned int pack2(float lo, float hi) {
    return (unsigned int)f2bf(lo) | ((unsigned int)f2bf(hi) << 16);
}
// A fragment: Wt[(k8*M + oc)*4 + j2]
__device__ __forceinline__ bf16x8 loadA(const unsigned int* __restrict__ W, int k8, int M, int oc) {
    U4 r; r.v = *(const uint4*)(W + (((size_t)k8 * M + oc) << 2));
    return r.h;
}
// B fragment (k-panel): one dwordx4 at u32-index (row*BC + b)*4
__device__ __forceinline__ bf16x8 loadB4(const unsigned int* __restrict__ base, size_t idx) {
    U4 r; r.v = *(const uint4*)(base + (idx << 2));
    return r.h;
}
// B fragment (pair rows, conv1 only): 4 dwords at stride BC
__device__ __forceinline__ bf16x8 loadBp(const unsigned int* __restrict__ p, size_t BC) {
    U4 r; r.u[0] = p[0]; r.u[1] = p[BC]; r.u[2] = p[2 * BC]; r.u[3] = p[3 * BC];
    return r.h;
}
#define MFMA(a, b, c) __builtin_amdgcn_mfma_f32_16x16x32_bf16((a), (b), (c), 0, 0, 0)

// bijective XCD swizzle (m204)
__device__ __forceinline__ int xcd_swz(int L, int nwg) {
    int q = nwg >> 3, r = nwg & 7;
    int x = L & 7, i = L >> 3;
    return (x < r ? x * (q + 1) : r * (q + 1) + (x - r) * q) + i;
}

// k-panel epilogue store: lane writes its 2 u32 (8B) of the out row's uint4
__device__ __forceinline__ void storeK(unsigned int* __restrict__ out,
                                       size_t row, size_t BC, size_t bcol,
                                       int lg, unsigned int u0, unsigned int u1) {
    uint2 v; v.x = u0; v.y = u1;
    *(uint2*)(out + ((row * BC + bcol) << 2) + ((lg & 1) << 1)) = v;
}

// ---------------- weight prepack (bf16, A-fragment layout) ----------------
// W1t: M=32,  K=192   k = c*64 + kh*8 + kw        (24 k8)   3072 u32
// W2t: M=64,  K=512   k = (kh*4+kw)*32 + ic       (64 k8)   16384 u32
// W3t: M=64,  K=576   k = (kh*3+kw)*64 + ic       (72 k8)   18432 u32
// Wpt: M=256, K=16384 k' = s3*64 + oc3            (2048 k8) 2097152 u32
// Wgt: M=256, K=256                               (32 k8)   32768 u32
// Wh1t:M=256, K=320                               (40 k8)   40960 u32
__global__ __launch_bounds__(256) void prepack(
    const float* __restrict__ W1, const float* __restrict__ W2,
    const float* __restrict__ W3, const float* __restrict__ Wp,
    const float* __restrict__ Wg, const float* __restrict__ Wh1,
    unsigned int* __restrict__ W1t, unsigned int* __restrict__ W2t,
    unsigned int* __restrict__ W3t, unsigned int* __restrict__ Wpt,
    unsigned int* __restrict__ Wgt, unsigned int* __restrict__ Wh1t)
{
    int i = blockIdx.x * 256 + threadIdx.x;
    if (i < 3072) {
        int j2 = i & 3, oc = (i >> 2) & 31, k8 = i >> 7;
        int c = k8 >> 3, kh = k8 & 7, kw = 2 * j2;
        const float* s = W1 + ((oc * 3 + c) * 8 + kh) * 8;
        W1t[i] = pack2(s[kw], s[kw + 1]);
    } else if (i < 19456) {
        int j = i - 3072;
        int j2 = j & 3, oc = (j >> 2) & 63, k8 = j >> 8;
        int tap = k8 >> 2, ic = (k8 & 3) * 8 + 2 * j2;
        int kh = tap >> 2, kw = tap & 3;
        float a = W2[((oc * 32 + ic) * 4 + kh) * 4 + kw];
        float b = W2[((oc * 32 + ic + 1) * 4 + kh) * 4 + kw];
        W2t[j] = pack2(a, b);
    } else if (i < 37888) {
        int j = i - 19456;
        int j2 = j & 3, oc = (j >> 2) & 63, k8 = j >> 8;
        int tap = k8 >> 3, ic = (k8 & 7) * 8 + 2 * j2;
        int kh = tap / 3, kw = tap % 3;
        float a = W3[((oc * 64 + ic) * 3 + kh) * 3 + kw];
        float b = W3[((oc * 64 + ic + 1) * 3 + kh) * 3 + kw];
        W3t[j] = pack2(a, b);
    } else if (i < 2135040) {
        int j = i - 37888;
        int j2 = j & 3, n = (j >> 2) & 255, k8 = j >> 10;
        int s3 = k8 >> 3, oc = (k8 & 7) * 8 + 2 * j2;
        float a = Wp[(size_t)(oc * 256 + s3) * 256 + n];
        float b = Wp[(size_t)((oc + 1) * 256 + s3) * 256 + n];
        Wpt[j] = pack2(a, b);
    } else if (i < 2167808) {
        int j = i - 2135040;
        int j2 = j & 3, m = (j >> 2) & 255, k8 = j >> 10;
        int k = k8 * 8 + 2 * j2;
        Wgt[j] = pack2(Wg[k * 256 + m], Wg[(k + 1) * 256 + m]);
    } else if (i < 2208768) {
        int j = i - 2167808;
        int j2 = j & 3, m = (j >> 2) & 255, k8 = j >> 10;
        int k = k8 * 8 + 2 * j2;
        Wh1t[j] = pack2(Wh1[k * 256 + m], Wh1[(k + 1) * 256 + m]);
    }
}

// cam [512][84][84][3] fp32 -> camt32[((c*84+y)*42 + x2)*BC + b] bf16 x-pairs
__global__ __launch_bounds__(256) void transpose_cam(
    const float* __restrict__ cam, unsigned int* __restrict__ camt, int b0, int BC)
{
    __shared__ float lds[32][253];
    int yy = blockIdx.x;
    int bb = blockIdx.y * 32;
    int t = threadIdx.x;
    for (int f = t; f < 8064; f += 256) {
        int b = f / 252, p = f - b * 252;
        lds[b][p] = cam[(size_t)(b0 + bb + b) * 21168 + yy * 252 + p];
    }
    __syncthreads();
    for (int g = t; g < 4032; g += 256) {
        int b = g & 31, q = g >> 5;
        int c = q / 42, x2 = q - c * 42;
        unsigned int v = pack2(lds[b][6 * x2 + c], lds[b][6 * x2 + 3 + c]);
        camt[(size_t)((c * 84 + yy) * 42 + x2) * BC + bb + b] = v;
    }
}

// conv1: 3ch 84x84 -> 32ch 39x39, k=8 s=2. M=32, K=192. N=64/wave.
// out1 k-panel: [(p39*4 + icg)][b] uint4 (icg = oc/8)
__global__ __launch_bounds__(256) void conv1_mfma(
    const unsigned int* __restrict__ in32, const unsigned int* __restrict__ Wt,
    const float* __restrict__ bias, unsigned int* __restrict__ out32,
    int BC, int nspat)
{
    int wgid = xcd_swz(blockIdx.x, gridDim.x);
    int s = wgid % nspat;
    int bq = wgid / nspat;
    int oh = s / 39, ow = s - oh * 39;
    int wv = threadIdx.x >> 6, l = threadIdx.x & 63;
    int lg = l >> 4, lc = l & 15;
    const size_t sBC = (size_t)BC;
    size_t base = (size_t)bq * 256 + wv * 64 + lc;
    f32x4 acc[2][4] = {};
    int ybase = 2 * oh;
    #pragma unroll
    for (int sp = 0; sp < 3; sp++) {               // c = sp
        const int s0 = 2 * sp, s1 = s0 + 1;
        bf16x8 A0[2], A1[2], B0[4], B1[4];
        #pragma unroll
        for (int m = 0; m < 2; m++) {
            A0[m] = loadA(Wt, s0 * 4 + lg, 32, m * 16 + lc);
            A1[m] = loadA(Wt, s1 * 4 + lg, 32, m * 16 + lc);
        }
        const unsigned int* p0 = in32 + (size_t)((sp * 84 + ybase + lg) * 42 + ow) * sBC + base;
        const unsigned int* p1 = in32 + (size_t)((sp * 84 + ybase + 4 + lg) * 42 + ow) * sBC + base;
        #pragma unroll
        for (int g = 0; g < 4; g++) {
            B0[g] = loadBp(p0 + g * 16, sBC);
            B1[g] = loadBp(p1 + g * 16, sBC);
        }
        #pragma unroll
        for (int m = 0; m < 2; m++)
            #pragma unroll
            for (int g = 0; g < 4; g++)
                acc[m][g] = MFMA(A0[m], B0[g], acc[m][g]);
        #pragma unroll
        for (int m = 0; m < 2; m++)
            #pragma unroll
            for (int g = 0; g < 4; g++)
                acc[m][g] = MFMA(A1[m], B1[g], acc[m][g]);
    }
    #pragma unroll
    for (int m = 0; m < 2; m++) {
        float4 bv = *(const float4*)(bias + m * 16 + lg * 4);
        size_t row = (size_t)s * 4 + 2 * m + (lg >> 1);
        #pragma unroll
        for (int g = 0; g < 4; g++) {
            f32x4 a = acc[m][g];
            unsigned int u0 = pack2(fmaxf(a.x + bv.x, 0.f), fmaxf(a.y + bv.y, 0.f));
            unsigned int u1 = pack2(fmaxf(a.z + bv.z, 0.f), fmaxf(a.w + bv.w, 0.f));
            storeK(out32, row, sBC, base + g * 16, lg, u0, u1);
        }
    }
}

// conv2: 32ch 39x39 -> 64ch 18x18, k=4 s=2. M=64, K=512 (16 steps = 16 taps).
// in k-panel G=4, out k-panel G=8.
__global__ __launch_bounds__(256) void conv2_mfma(
    const unsigned int* __restrict__ in32, const unsigned int* __restrict__ Wt,
    const float* __restrict__ bias, unsigned int* __restrict__ out32,
    int BC, int nspat)
{
    int wgid = xcd_swz(blockIdx.x, gridDim.x);
    int s = wgid % nspat;
    int bq = wgid / nspat;
    int oh = s / 18, ow = s - oh * 18;
    int wv = threadIdx.x >> 6, l = threadIdx.x & 63;
    int lg = l >> 4, lc = l & 15;
    const size_t sBC = (size_t)BC;
    size_t base = (size_t)bq * 256 + wv * 64 + lc;
    f32x4 acc[4][4] = {};
    int ybase = 2 * oh, xbase = 2 * ow;
    #pragma unroll
    for (int sp = 0; sp < 8; sp++) {
        const int s0 = 2 * sp, s1 = s0 + 1;
        bf16x8 A0[4], A1[4], B0[4], B1[4];
        #pragma unroll
        for (int m = 0; m < 4; m++) {
            A0[m] = loadA(Wt, s0 * 4 + lg, 64, m * 16 + lc);
            A1[m] = loadA(Wt, s1 * 4 + lg, 64, m * 16 + lc);
        }
        {   // tap = s0
            const int kh = s0 >> 2, kw = s0 & 3;
            size_t row = (size_t)(((ybase + kh) * 39 + xbase + kw) * 4 + lg);
            #pragma unroll
            for (int g = 0; g < 4; g++)
                B0[g] = loadB4(in32, row * sBC + base + g * 16);
        }
        {   // tap = s1
            const int kh = s1 >> 2, kw = s1 & 3;
            size_t row = (size_t)(((ybase + kh) * 39 + xbase + kw) * 4 + lg);
            #pragma unroll
            for (int g = 0; g < 4; g++)
                B1[g] = loadB4(in32, row * sBC + base + g * 16);
        }
        #pragma unroll
        for (int m = 0; m < 4; m++)
            #pragma unroll
            for (int g = 0; g < 4; g++)
                acc[m][g] = MFMA(A0[m], B0[g], acc[m][g]);
        #pragma unroll
        for (int m = 0; m < 4; m++)
            #pragma unroll
            for (int g = 0; g < 4; g++)
                acc[m][g] = MFMA(A1[m], B1[g], acc[m][g]);
    }
    #pragma unroll
    for (int m = 0; m < 4; m++) {
        float4 bv = *(const float4*)(bias + m * 16 + lg * 4);
        size_t row = (size_t)s * 8 + 2 * m + (lg >> 1);
        #pragma unroll
        for (int g = 0; g < 4; g++) {
            f32x4 a = acc[m][g];
            unsigned int u0 = pack2(fmaxf(a.x + bv.x, 0.f), fmaxf(a.y + bv.y, 0.f));
            unsigned int u1 = pack2(fmaxf(a.z + bv.z, 0.f), fmaxf(a.w + bv.w, 0.f));
            storeK(out32, row, sBC, base + g * 16, lg, u0, u1);
        }
    }
}

// conv3: 64ch 18x18 -> 64ch 16x16, k=3 s=1. M=64, K=576 (9 taps x 2 steps).
// in k-panel G=8, out (x3) k-panel G=8 rows = s3*8 + ocg.
__global__ __launch_bounds__(256) void conv3_mfma(
    const unsigned int* __restrict__ in32, const unsigned int* __restrict__ Wt,
    const float* __restrict__ bias, unsigned int* __restrict__ out32,
    int BC, int nspat)
{
    int wgid = xcd_swz(blockIdx.x, gridDim.x);
    int s = wgid % nspat;
    int bq = wgid / nspat;
    int oh = s >> 4, ow = s & 15;
    int wv = threadIdx.x >> 6, l = threadIdx.x & 63;
    int lg = l >> 4, lc = l & 15;
    const size_t sBC = (size_t)BC;
    size_t base = (size_t)bq * 256 + wv * 64 + lc;
    f32x4 acc[4][4] = {};
    #pragma unroll
    for (int sp = 0; sp < 9; sp++) {               // tap = sp
        const int s0 = 2 * sp, s1 = s0 + 1;
        const int kh = sp / 3, kw = sp - kh * 3;
        bf16x8 A0[4], A1[4], B0[4], B1[4];
        #pragma unroll
        for (int m = 0; m < 4; m++) {
            A0[m] = loadA(Wt, s0 * 4 + lg, 64, m * 16 + lc);
            A1[m] = loadA(Wt, s1 * 4 + lg, 64, m * 16 + lc);
        }
        size_t row0 = (size_t)(((oh + kh) * 18 + ow + kw) * 8 + lg);
        #pragma unroll
        for (int g = 0; g < 4; g++) {
            B0[g] = loadB4(in32, row0 * sBC + base + g * 16);
            B1[g] = loadB4(in32, (row0 + 4) * sBC + base + g * 16);
        }
        #pragma unroll
        for (int m = 0; m < 4; m++)
            #pragma unroll
            for (int g = 0; g < 4; g++)
                acc[m][g] = MFMA(A0[m], B0[g], acc[m][g]);
        #pragma unroll
        for (int m = 0; m < 4; m++)
            #pragma unroll
            for (int g = 0; g < 4; g++)
                acc[m][g] = MFMA(A1[m], B1[g], acc[m][g]);
    }
    #pragma unroll
    for (int m = 0; m < 4; m++) {
        float4 bv = *(const float4*)(bias + m * 16 + lg * 4);
        size_t row = (size_t)s * 8 + 2 * m + (lg >> 1);
        #pragma unroll
        for (int g = 0; g < 4; g++) {
            f32x4 a = acc[m][g];
            unsigned int u0 = pack2(fmaxf(a.x + bv.x, 0.f), fmaxf(a.y + bv.y, 0.f));
            unsigned int u1 = pack2(fmaxf(a.z + bv.z, 0.f), fmaxf(a.w + bv.w, 0.f));
            storeK(out32, row, sBC, base + g * 16, lg, u0, u1);
        }
    }
}

// proj: x3 k-panel (K=16384) @ Wpt -> partial (f32x4 rows), K-split 32
__global__ __launch_bounds__(256) void proj_mfma(
    const unsigned int* __restrict__ x3, const unsigned int* __restrict__ Wpt,
    float* __restrict__ partial, int BC)
{
    int wgid = xcd_swz(blockIdx.x, gridDim.x);
    int rem = wgid & 127;            // 4 mq x 32 kseg
    int bq = wgid >> 7;
    int mq = rem & 3;
    int kseg = rem >> 2;
    int wv = threadIdx.x >> 6, l = threadIdx.x & 63;
    int lg = l >> 4, lc = l & 15;
    const size_t sBC = (size_t)BC;
    size_t base = (size_t)bq * 256 + wv * 64 + lc;
    f32x4 acc[4][4] = {};
    #pragma unroll
    for (int sp = 0; sp < 8; sp++) {
        const int k8b = kseg * 64 + sp * 8;        // = (kseg*8+sp)*8
        bf16x8 A0[4], A1[4], B0[4], B1[4];
        #pragma unroll
        for (int m = 0; m < 4; m++) {
            A0[m] = loadA(Wpt, k8b + lg, 256, mq * 64 + m * 16 + lc);
            A1[m] = loadA(Wpt, k8b + 4 + lg, 256, mq * 64 + m * 16 + lc);
        }
        #pragma unroll
        for (int g = 0; g < 4; g++) {
            B0[g] = loadB4(x3, (size_t)(k8b + lg) * sBC + base + g * 16);
            B1[g] = loadB4(x3, (size_t)(k8b + 4 + lg) * sBC + base + g * 16);
        }
        #pragma unroll
        for (int m = 0; m < 4; m++)
            #pragma unroll
            for (int g = 0; g < 4; g++)
                acc[m][g] = MFMA(A0[m], B0[g], acc[m][g]);
        #pragma unroll
        for (int m = 0; m < 4; m++)
            #pragma unroll
            for (int g = 0; g < 4; g++)
                acc[m][g] = MFMA(A1[m], B1[g], acc[m][g]);
    }
    // partial row4 = kseg*64 + mq*16 + m*4 + lg ; f32x4 per (row4, b)
    #pragma unroll
    for (int m = 0; m < 4; m++) {
        size_t row4 = (size_t)kseg * 64 + mq * 16 + m * 4 + lg;
        #pragma unroll
        for (int g = 0; g < 4; g++)
            *(f32x4*)(partial + ((row4 * sBC + base + g * 16) << 2)) = acc[m][g];
    }
}

// reduce K-split partials + bias + relu -> cf16 k-panel [n8][512] uint4
__global__ __launch_bounds__(256) void reduce_k(
    const float* __restrict__ partial, const float* __restrict__ bp,
    unsigned int* __restrict__ cf16, int b0, int BC, int bcShift)
{
    int i = blockIdx.x * 256 + threadIdx.x;
    int bl = i & (BC - 1);
    int k8 = i >> bcShift;                      // 0..31
    f32x4 S0 = {}, S1 = {};
    for (int seg = 0; seg < 32; seg++) {
        const float* p = partial + (((size_t)(seg * 64 + k8 * 2) * BC + bl) << 2);
        S0 += *(const f32x4*)p;
        S1 += *(const f32x4*)(p + (BC << 2));
    }
    int n = k8 * 8;
    uint4 u;
    u.x = pack2(fmaxf(S0.x + bp[n + 0], 0.f), fmaxf(S0.y + bp[n + 1], 0.f));
    u.y = pack2(fmaxf(S0.z + bp[n + 2], 0.f), fmaxf(S0.w + bp[n + 3], 0.f));
    u.z = pack2(fmaxf(S1.x + bp[n + 4], 0.f), fmaxf(S1.y + bp[n + 5], 0.f));
    u.w = pack2(fmaxf(S1.z + bp[n + 6], 0.f), fmaxf(S1.w + bp[n + 7], 0.f));
    *(uint4*)(cf16 + (((size_t)k8 * 512 + b0 + bl) << 2)) = u;
}

// gat_prep: hNb[b][256] = camfeat @ Wg[:256]  (M=256,K=256,N=512)
__global__ __launch_bounds__(64) void gat_prep(
    const unsigned int* __restrict__ cf16, const unsigned int* __restrict__ Wgt,
    float* __restrict__ hNb)
{
    int mq = blockIdx.x, bq = blockIdx.y;
    int l = threadIdx.x, lg = l >> 4, lc = l & 15;
    size_t bcol = (size_t)bq * 32 + lc;
    f32x4 acc[4][2] = {};
    #pragma unroll
    for (int sp = 0; sp < 4; sp++) {
        const int s0 = 2 * sp, s1 = s0 + 1;
        bf16x8 A0[4], A1[4], B0[2], B1[2];
        #pragma unroll
        for (int m = 0; m < 4; m++) {
            A0[m] = loadA(Wgt, s0 * 4 + lg, 256, mq * 64 + m * 16 + lc);
            A1[m] = loadA(Wgt, s1 * 4 + lg, 256, mq * 64 + m * 16 + lc);
        }
        #pragma unroll
        for (int g = 0; g < 2; g++) {
            B0[g] = loadB4(cf16, (size_t)(s0 * 4 + lg) * 512 + bcol + g * 16);
            B1[g] = loadB4(cf16, (size_t)(s1 * 4 + lg) * 512 + bcol + g * 16);
        }
        #pragma unroll
        for (int m = 0; m < 4; m++) {
            acc[m][0] = MFMA(A0[m], B0[0], acc[m][0]);
            acc[m][1] = MFMA(A0[m], B0[1], acc[m][1]);
            acc[m][0] = MFMA(A1[m], B1[0], acc[m][0]);
            acc[m][1] = MFMA(A1[m], B1[1], acc[m][1]);
        }
    }
    #pragma unroll
    for (int m = 0; m < 4; m++) {
        #pragma unroll
        for (int g = 0; g < 2; g++) {
            size_t b = (size_t)bq * 32 + g * 16 + lc;
            int row0 = mq * 64 + m * 16 + lg * 4;
            *(f32x4*)(hNb + b * 256 + row0) = acc[m][g];
        }
    }
}

// gat_mid: per-batch attention row + agent gather + id emb -> af16 k-panel
__global__ __launch_bounds__(256) void gat_mid(
    const float* __restrict__ hNb, const float* __restrict__ pos,
    const float* __restrict__ tpos, const int* __restrict__ aidx,
    const float* __restrict__ Wg, const float* __restrict__ asrc, const float* __restrict__ adst,
    const float* __restrict__ Wid, const float* __restrict__ bid,
    unsigned int* __restrict__ af16)
{
    int b = blockIdx.x, t = threadIdx.x;
    __shared__ float hN[16][256];
    __shared__ float srcv[16][2], dstv[16][2];
    __shared__ float alpha[16][2];
    __shared__ float af[320];
    __shared__ unsigned int adjm_s;

    int ai = aidx[b];
    float basev = hNb[(size_t)b * 256 + t];
    float rw0 = Wg[65536 + t], rw1 = Wg[65792 + t], rw2 = Wg[66048 + t];
    float px = pos[b * 3 + 0], py = pos[b * 3 + 1], pz = pos[b * 3 + 2];
    for (int n = 0; n < 16; n++) {
        float r0 = tpos[(b * 16 + n) * 3 + 0] - px;
        float r1 = tpos[(b * 16 + n) * 3 + 1] - py;
        float r2 = tpos[(b * 16 + n) * 3 + 2] - pz;
        hN[n][t] = basev + r0 * rw0 + r1 * rw1 + r2 * rw2;
    }

    if (t < 64) {
        bool on = false;
        if (t < 16 && t != ai) {
            float dx = tpos[(b * 16 + ai) * 3 + 0] - tpos[(b * 16 + t) * 3 + 0];
            float dy = tpos[(b * 16 + ai) * 3 + 1] - tpos[(b * 16 + t) * 3 + 1];
            float dz = tpos[(b * 16 + ai) * 3 + 2] - tpos[(b * 16 + t) * 3 + 2];
            on = (dx * dx + dy * dy + dz * dz) < 10000.0f;
        }
        unsigned long long m = __ballot(on);
        if (t == 0) adjm_s = (m == 0ull) ? (1u << ai) : (unsigned int)m;
    }
    __syncthreads();

    {
        int p = t >> 3, sub = t & 7;
        int j = p >> 1, h = p & 1;
        float s1 = 0.f, s2 = 0.f;
        #pragma unroll
        for (int dd = 0; dd < 16; dd++) {
            int d = h * 128 + sub * 16 + dd;
            float v = hN[j][d];
            s1 += v * asrc[d];
            s2 += v * adst[d];
        }
        s1 += __shfl_xor(s1, 1); s1 += __shfl_xor(s1, 2); s1 += __shfl_xor(s1, 4);
        s2 += __shfl_xor(s2, 1); s2 += __shfl_xor(s2, 2); s2 += __shfl_xor(s2, 4);
        if (sub == 0) { srcv[j][h] = s1; dstv[j][h] = s2; }
    }
    __syncthreads();

    if (t < 32) {
        int j = t & 15, h = t >> 4;
        unsigned int am = adjm_s;
        float e = srcv[ai][h] + dstv[j][h];
        e = (e > 0.f) ? e : 0.2f * e;
        e = ((am >> j) & 1u) ? e : -1e9f;
        float mx = e;
        mx = fmaxf(mx, __shfl_xor(mx, 1));
        mx = fmaxf(mx, __shfl_xor(mx, 2));
        mx = fmaxf(mx, __shfl_xor(mx, 4));
        mx = fmaxf(mx, __shfl_xor(mx, 8));
        float ex = __expf(e - mx);
        float sm = ex;
        sm += __shfl_xor(sm, 1); sm += __shfl_xor(sm, 2);
        sm += __shfl_xor(sm, 4); sm += __shfl_xor(sm, 8);
        alpha[j][h] = ex / sm;
    }
    __syncthreads();

    {
        int h = t >> 7;
        float o = 0.f;
        #pragma unroll
        for (int j = 0; j < 16; j++) o += alpha[j][h] * hN[j][t];
        o = (o > 0.f) ? o : (__expf(o) - 1.f);
        af[t] = o;
    }
    if (t < 64) {
        float v = (float)ai * Wid[t] + bid[t];
        af[256 + t] = fmaxf(v, 0.f);
    }
    __syncthreads();

    if (t < 40) {
        uint4 u;
        u.x = pack2(af[t * 8 + 0], af[t * 8 + 1]);
        u.y = pack2(af[t * 8 + 2], af[t * 8 + 3]);
        u.z = pack2(af[t * 8 + 4], af[t * 8 + 5]);
        u.w = pack2(af[t * 8 + 6], af[t * 8 + 7]);
        *(uint4*)(af16 + (((size_t)t * 512 + b) << 2)) = u;
    }
}

// head_mfma: zf[row][b] = relu(af @ Wh1 + bh1)  (M=256,K=320,N=512)
__global__ __launch_bounds__(64) void head_mfma(
    const unsigned int* __restrict__ af16, const unsigned int* __restrict__ Wh1t,
    const float* __restrict__ bh1, float* __restrict__ zf)
{
    int mq = blockIdx.x, bq = blockIdx.y;
    int l = threadIdx.x, lg = l >> 4, lc = l & 15;
    size_t bcol = (size_t)bq * 32 + lc;
    f32x4 acc[4][2] = {};
    #pragma unroll
    for (int sp = 0; sp < 5; sp++) {
        const int s0 = 2 * sp, s1 = s0 + 1;
        bf16x8 A0[4], A1[4], B0[2], B1[2];
        #pragma unroll
        for (int m = 0; m < 4; m++) {
            A0[m] = loadA(Wh1t, s0 * 4 + lg, 256, mq * 64 + m * 16 + lc);
            A1[m] = loadA(Wh1t, s1 * 4 + lg, 256, mq * 64 + m * 16 + lc);
        }
        #pragma unroll
        for (int g = 0; g < 2; g++) {
            B0[g] = loadB4(af16, (size_t)(s0 * 4 + lg) * 512 + bcol + g * 16);
            B1[g] = loadB4(af16, (size_t)(s1 * 4 + lg) * 512 + bcol + g * 16);
        }
        #pragma unroll
        for (int m = 0; m < 4; m++) {
            acc[m][0] = MFMA(A0[m], B0[0], acc[m][0]);
            acc[m][1] = MFMA(A0[m], B0[1], acc[m][1]);
            acc[m][0] = MFMA(A1[m], B1[0], acc[m][0]);
            acc[m][1] = MFMA(A1[m], B1[1], acc[m][1]);
        }
    }
    #pragma unroll
    for (int m = 0; m < 4; m++) {
        int row0 = mq * 64 + m * 16 + lg * 4;
        float4 bv = *(const float4*)(bh1 + row0);
        #pragma unroll
        for (int g = 0; g < 2; g++) {
            f32x4 a = acc[m][g];
            size_t b = (size_t)bq * 32 + g * 16 + lc;
            float* pp = zf + (size_t)row0 * 512 + b;
            pp[0]       = fmaxf(a.x + bv.x, 0.f);
            pp[512]     = fmaxf(a.y + bv.y, 0.f);
            pp[2 * 512] = fmaxf(a.z + bv.z, 0.f);
            pp[3 * 512] = fmaxf(a.w + bv.w, 0.f);
        }
    }
}

// logits: out[b][6] = zf[:,b] @ Wh2 + bh2
__global__ __launch_bounds__(256) void logits_k(
    const float* __restrict__ zf, const float* __restrict__ Wh2,
    const float* __restrict__ bh2, float* __restrict__ out)
{
    __shared__ float Ws[1536];
    int t = threadIdx.x;
    int b = blockIdx.x * 256 + t;
    for (int f = t; f < 1536; f += 256) Ws[f] = Wh2[f];
    __syncthreads();
    float acc[6];
    #pragma unroll
    for (int j = 0; j < 6; j++) acc[j] = bh2[j];
    for (int k = 0; k < 256; k++) {
        float zv = zf[(size_t)k * 512 + b];
        #pragma unroll
        for (int j = 0; j < 6; j++) acc[j] += zv * Ws[k * 6 + j];
    }
    #pragma unroll
    for (int j = 0; j < 6; j++) out[b * 6 + j] = acc[j];
}

extern "C" void kernel_launch(void* const* d_in, const int* in_sizes, int n_in,
                              void* d_out, int out_size, void* d_ws, size_t ws_size,
                              hipStream_t stream)
{
    const float* cam  = (const float*)d_in[0];
    const float* pos  = (const float*)d_in[1];
    const float* tpos = (const float*)d_in[2];
    const int*   aidx = (const int*)d_in[3];
    const float* W1   = (const float*)d_in[4];
    const float* b1   = (const float*)d_in[5];
    const float* W2   = (const float*)d_in[6];
    const float* b2   = (const float*)d_in[7];
    const float* W3   = (const float*)d_in[8];
    const float* b3   = (const float*)d_in[9];
    const float* Wp   = (const float*)d_in[10];
    const float* bp   = (const float*)d_in[11];
    const float* Wid  = (const float*)d_in[12];
    const float* bid  = (const float*)d_in[13];
    const float* Wg   = (const float*)d_in[14];
    const float* asrc = (const float*)d_in[15];
    const float* adst = (const float*)d_in[16];
    const float* Wh1  = (const float*)d_in[17];
    const float* bh1  = (const float*)d_in[18];
    const float* Wh2  = (const float*)d_in[19];
    const float* bh2  = (const float*)d_in[20];
    float* out = (float*)d_out;

    // batch chunk (multiple of 256): per-chunk u32 = 51304*BC ; fixed = 2,618,368
    int BC = 256;
    if (((size_t)51304 * 512 + 2618368) * 4 <= ws_size) BC = 512;
    int bcShift = (BC == 512) ? 9 : 8;
    int nbq2 = BC >> 8;                         // 256-batch groups per chunk

    unsigned int* ws32 = (unsigned int*)d_ws;
    unsigned int* RA  = ws32;                                  // camt / out2
    unsigned int* RB  = RA + (size_t)10584 * BC;               // out1
    unsigned int* RC  = RB + (size_t)24336 * BC;               // x3
    float*        RD  = (float*)(RC + (size_t)8192 * BC);      // partial
    unsigned int* W1t = (unsigned int*)(RD + (size_t)8192 * BC);
    unsigned int* W2t  = W1t + 3072;
    unsigned int* W3t  = W2t + 16384;
    unsigned int* Wpt  = W3t + 18432;
    unsigned int* Wgt  = Wpt + 2097152;
    unsigned int* Wh1t = Wgt + 32768;
    unsigned int* cf16 = Wh1t + 40960;                         // 32 x 512 uint4
    float*        hNb  = (float*)(cf16 + 65536);               // 512 x 256
    unsigned int* af16 = (unsigned int*)(hNb + 131072);        // 40 x 512 uint4
    float*        zf   = (float*)(af16 + 81920);               // 256 x 512

    prepack<<<8628, 256, 0, stream>>>(W1, W2, W3, Wp, Wg, Wh1,
                                      W1t, W2t, W3t, Wpt, Wgt, Wh1t);

    for (int b0 = 0; b0 < 512; b0 += BC) {
        transpose_cam<<<dim3(84, BC / 32), 256, 0, stream>>>(cam, RA, b0, BC);
        conv1_mfma<<<1521 * nbq2, 256, 0, stream>>>(RA, W1t, b1, RB, BC, 1521);
        conv2_mfma<<<324 * nbq2, 256, 0, stream>>>(RB, W2t, b2, RA, BC, 324);
        conv3_mfma<<<256 * nbq2, 256, 0, stream>>>(RA, W3t, b3, RC, BC, 256);
        proj_mfma<<<128 * nbq2, 256, 0, stream>>>(RC, Wpt, RD, BC);
        reduce_k<<<(32 * BC) / 256, 256, 0, stream>>>(RD, bp, cf16, b0, BC, bcShift);
    }
    gat_prep<<<dim3(4, 16), 64, 0, stream>>>(cf16, Wgt, hNb);
    gat_mid<<<512, 256, 0, stream>>>(hNb, pos, tpos, aidx, Wg, asrc, adst,
                                     Wid, bid, af16);
    head_mfma<<<dim3(4, 16), 64, 0, stream>>>(af16, Wh1t, bh1, zf);
    logits_k<<<2, 256, 0, stream>>>(zf, Wh2, bh2, out);
}